// Round 2
// baseline (453.174 us; speedup 1.0000x reference)
//
#include <hip/hip_runtime.h>
#include <stdint.h>

#define EPSF 1e-5f
#define MAXNF (1.0f - 1e-5f)

typedef __attribute__((ext_vector_type(8))) short short8;
typedef __attribute__((ext_vector_type(4))) float floatx4;

__device__ __forceinline__ unsigned short f2bf(float f){
  union { float f; uint32_t u; } v; v.f = f;
  return (unsigned short)((v.u + 0x7FFFu + ((v.u >> 16) & 1u)) >> 16);
}
__device__ __forceinline__ float bf2f(unsigned short s){
  union { uint32_t u; float f; } v; v.u = ((uint32_t)s) << 16;
  return v.f;
}
__device__ __forceinline__ float4 bf2f4(ushort4 s){
  return make_float4(bf2f(s.x), bf2f(s.y), bf2f(s.z), bf2f(s.w));
}
__device__ __forceinline__ ushort4 f2bf4(float4 f){
  ushort4 r; r.x=f2bf(f.x); r.y=f2bf(f.y); r.z=f2bf(f.z); r.w=f2bf(f.w); return r;
}

__device__ __forceinline__ void gload16(const void* g, void* l){
  __builtin_amdgcn_global_load_lds(
      (__attribute__((address_space(1))) void*)(uintptr_t)g,
      (__attribute__((address_space(3))) void*)l, 16, 0, 0);
}

// ---------------- cast to bf16 + per-row (1024) norm ----------------
__global__ void cast_norm_k(const float* __restrict__ X, unsigned short* __restrict__ Xbf,
                            float* __restrict__ nrm){
  const int row = blockIdx.x, t = threadIdx.x;
  const float4 v = ((const float4*)(X + (size_t)row*1024))[t];
  ((ushort4*)(Xbf + (size_t)row*1024))[t] = f2bf4(v);
  float ss = v.x*v.x + v.y*v.y + v.z*v.z + v.w*v.w;
  #pragma unroll
  for (int o = 32; o; o >>= 1) ss += __shfl_down(ss, o);
  __shared__ float red[4];
  const int lane = t & 63, w = t >> 6;
  if (lane == 0) red[w] = ss;
  __syncthreads();
  if (t == 0) nrm[row] = sqrtf(red[0] + red[1] + red[2] + red[3]);
}

// ---------------- weight transpose+cast: Wt[n][k] = bf16(W[k][n]) ----------------
__global__ void wcast_k(const float* __restrict__ W, unsigned short* __restrict__ Wt){
  __shared__ float tile[32][33];
  const int tx = threadIdx.x, ty = threadIdx.y;     // 32 x 8
  const int k0 = blockIdx.x * 32, n0 = blockIdx.y * 32;
  #pragma unroll
  for (int i = 0; i < 4; ++i)
    tile[ty + i*8][tx] = W[(size_t)(k0 + ty + i*8) * 1024 + n0 + tx];
  __syncthreads();
  #pragma unroll
  for (int i = 0; i < 4; ++i)
    Wt[(size_t)(n0 + ty + i*8) * 1024 + k0 + tx] = f2bf(tile[tx][ty + i*8]);
}

// ---------------- bf16 MFMA GEMM: C[m][n] = bf16( sum_k A[m][k] * Bt[n][k] ) ----------------
// M=16384, N=1024, K=1024. BM=128, BN=256, BK=32. 512 threads = 8 waves (2x4),
// wave tile 64x64 = 4x4 fragments of 16x16x32. Double-buffered LDS via
// global_load_lds (linear dest); XOR chunk swizzle (chunk ^= row&3) applied on the
// global source and on the ds_read address (both-sides rule) -> a wave's
// ds_read_b128 hits all 32 banks perfectly balanced (8 accesses/bank = minimum).
#define GBM 128
#define GBN 256
#define GBK 32
#define GKD 1024

__global__ __launch_bounds__(512) void gemm_k(const unsigned short* __restrict__ A,
                                              const unsigned short* __restrict__ Bt,
                                              unsigned short* __restrict__ C){
  __shared__ unsigned short smem[2*4096 + 2*8192];   // A: 2x(128x32), B: 2x(256x32)
  unsigned short* As = smem;
  unsigned short* Bs = smem + 2*4096;
  const int tid = threadIdx.x;
  const int lane = tid & 63, w = tid >> 6;
  const int wr = w >> 2, wc = w & 3;
  const int lr = lane & 15, kg = lane >> 4;
  const int row0 = blockIdx.y * GBM, col0 = blockIdx.x * GBN;

  int aoff[4], boff[4];
  #pragma unroll
  for (int a = 0; a < 4; ++a){
    const int r = wr*64 + a*16 + lr;
    aoff[a] = r*32 + ((kg ^ (r & 3)) << 3);
  }
  #pragma unroll
  for (int b = 0; b < 4; ++b){
    const int r = wc*64 + b*16 + lr;
    boff[b] = r*32 + ((kg ^ (r & 3)) << 3);
  }

  floatx4 acc[4][4] = {};

  auto stage = [&](int buf, int kt){
    {
      const int flat = tid;                       // 512 chunks for A tile
      const int r = flat >> 2, cp = flat & 3, c = cp ^ (r & 3);
      gload16(A + (size_t)(row0 + r)*GKD + kt*GBK + c*8, As + buf*4096 + flat*8);
    }
    #pragma unroll
    for (int i = 0; i < 2; ++i){                  // 1024 chunks for B tile
      const int flat = i*512 + tid;
      const int r = flat >> 2, cp = flat & 3, c = cp ^ (r & 3);
      gload16(Bt + (size_t)(col0 + r)*GKD + kt*GBK + c*8, Bs + buf*8192 + flat*8);
    }
  };

  stage(0, 0);
  __syncthreads();
  int cur = 0;
  for (int kt = 0; kt < GKD/GBK; ++kt){
    if (kt + 1 < GKD/GBK) stage(cur ^ 1, kt + 1);
    const unsigned short* as = As + cur*4096;
    const unsigned short* bs = Bs + cur*8192;
    short8 af[4], bfv[4];
    #pragma unroll
    for (int a = 0; a < 4; ++a) af[a] = *(const short8*)(as + aoff[a]);
    #pragma unroll
    for (int b = 0; b < 4; ++b) bfv[b] = *(const short8*)(bs + boff[b]);
    #pragma unroll
    for (int a = 0; a < 4; ++a)
      #pragma unroll
      for (int b = 0; b < 4; ++b)
        acc[a][b] = __builtin_amdgcn_mfma_f32_16x16x32_bf16(af[a], bfv[b], acc[a][b], 0, 0, 0);
    __syncthreads();
    cur ^= 1;
  }

  const int crow0 = row0 + wr*64;
  const int ccol = col0 + wc*64 + lr;
  #pragma unroll
  for (int a = 0; a < 4; ++a){
    #pragma unroll
    for (int j = 0; j < 4; ++j){
      const int r = crow0 + a*16 + kg*4 + j;
      unsigned short* cp = C + (size_t)r*1024 + ccol;
      #pragma unroll
      for (int b = 0; b < 4; ++b) cp[b*16] = f2bf(acc[a][b][j]);
    }
  }
}

// ---------------- per-ball Mobius helpers (thread t owns ball t) ----------------
__device__ __forceinline__ float dot4(const float4 a, const float4 b){
  return a.x*b.x + a.y*b.y + a.z*b.z + a.w*b.w;
}
__device__ __forceinline__ float4 scal4(const float4 a, float s){
  return make_float4(a.x*s, a.y*s, a.z*s, a.w*s);
}
__device__ __forceinline__ float clipn(float n){ return fminf(fmaxf(n, EPSF), MAXNF); }

__device__ __forceinline__ float4 mob_add4(const float4 u, const float4 v){
  const float uv = dot4(u,v), uu = dot4(u,u), vv = dot4(v,v);
  const float cu = 1.f + 2.f*uv + vv, cv = 1.f - uu;
  const float inv = 1.f / fmaxf(1.f + 2.f*uv + uu*vv, EPSF);
  return make_float4((cu*u.x + cv*v.x)*inv, (cu*u.y + cv*v.y)*inv,
                     (cu*u.z + cv*v.z)*inv, (cu*u.w + cv*v.w)*inv);
}

__device__ __forceinline__ float4 logmap_sig4(const float4 y){
  const float n = sqrtf(dot4(y,y));
  const float nc = clipn(n);
  const float s = atanhf(nc)/nc;
  return make_float4(1.f/(1.f+expf(-s*y.x)), 1.f/(1.f+expf(-s*y.y)),
                     1.f/(1.f+expf(-s*y.z)), 1.f/(1.f+expf(-s*y.w)));
}

__device__ __forceinline__ float4 mob_pp4(const float4 x, const float4 u){
  const float4 ux = make_float4(u.x*x.x, u.y*x.y, u.z*x.z, u.w*x.w);
  const float xn = clipn(sqrtf(dot4(x,x)));
  const float uxn = fmaxf(sqrtf(dot4(ux,ux)), EPSF);
  const float s = tanhf(uxn/xn*atanhf(xn))/uxn;
  return scal4(ux, s);
}

// ---------------- epilogue 1: z, r gates; rph; Ux (all bf16, in-place) ----------------
__global__ void epi1_k(unsigned short* mzh_z,        // in: Mz_h, out: z
                       unsigned short* mzx_rph,      // in: Mz_x, out: rph (d_out scratch)
                       const unsigned short* mrh,    // in: Mr_h  (d_out scratch)
                       unsigned short* mrx_ux,       // in: Mr_x, out: Ux
                       const float* hidden, const float* bz, const float* br,
                       const float* h_nrm, const float* x_nrm, float* rph_nrm){
  const int row = blockIdx.x, t = threadIdx.x;
  const int lane = t & 63, w = t >> 6;
  const size_t base = (size_t)row*1024;
  const float4 mzh  = bf2f4(((const ushort4*)(mzh_z + base))[t]);
  const float4 mzx4 = bf2f4(((const ushort4*)(mzx_rph + base))[t]);
  const float4 mrh4 = bf2f4(((const ushort4*)(mrh + base))[t]);
  const float4 mrx4 = bf2f4(((const ushort4*)(mrx_ux + base))[t]);
  float s0 = dot4(mzh,mzh), s1 = dot4(mzx4,mzx4), s2 = dot4(mrh4,mrh4), s3 = dot4(mrx4,mrx4);
  #pragma unroll
  for (int o = 32; o; o >>= 1){
    s0 += __shfl_down(s0,o); s1 += __shfl_down(s1,o);
    s2 += __shfl_down(s2,o); s3 += __shfl_down(s3,o);
  }
  __shared__ float red[4][4];
  if (lane == 0){ red[w][0]=s0; red[w][1]=s1; red[w][2]=s2; red[w][3]=s3; }
  __syncthreads();
  const float nMzh = fmaxf(sqrtf(red[0][0]+red[1][0]+red[2][0]+red[3][0]), EPSF);
  const float nMzx = fmaxf(sqrtf(red[0][1]+red[1][1]+red[2][1]+red[3][1]), EPSF);
  const float nMrh = fmaxf(sqrtf(red[0][2]+red[1][2]+red[2][2]+red[3][2]), EPSF);
  const float nMrx = fmaxf(sqrtf(red[0][3]+red[1][3]+red[2][3]+red[3][3]), EPSF);
  const float hnc = clipn(h_nrm[row]), xnc = clipn(x_nrm[row]);
  const float atH = atanhf(hnc), atX = atanhf(xnc);
  const float swz = tanhf(nMzh/hnc*atH)/nMzh;
  const float suz = tanhf(nMzx/xnc*atX)/nMzx;
  const float swr = tanhf(nMrh/hnc*atH)/nMrh;
  const float sur = tanhf(nMrx/xnc*atX)/nMrx;
  const float4 bz4 = ((const float4*)bz)[t];
  const float4 br4 = ((const float4*)br)[t];
  const float4 z4 = logmap_sig4(mob_add4(mob_add4(scal4(mzh,swz), scal4(mzx4,suz)), bz4));
  const float4 UxR = scal4(mrx4, sur);
  const float4 r4 = logmap_sig4(mob_add4(mob_add4(scal4(mrh4,swr), UxR), br4));
  ((ushort4*)(mzh_z + base))[t] = f2bf4(z4);     // z overwrites Mz_h
  ((ushort4*)(mrx_ux + base))[t] = f2bf4(UxR);   // Ux overwrites Mr_x
  const float4 h4 = ((const float4*)(hidden + base))[t];
  const float4 rph = mob_pp4(h4, r4);
  ((ushort4*)(mzx_rph + base))[t] = f2bf4(rph);  // rph overwrites Mz_x (same bytes, same thread)
  float sr = dot4(rph, rph);
  #pragma unroll
  for (int o = 32; o; o >>= 1) sr += __shfl_down(sr,o);
  __syncthreads();
  if (lane == 0) red[w][0] = sr;
  __syncthreads();
  if (t == 0) rph_nrm[row] = sqrtf(red[0][0]+red[1][0]+red[2][0]+red[3][0]);
}

// ---------------- epilogue 2: h_tilde, final new_h ----------------
__global__ void epi2_k(const unsigned short* mh, const unsigned short* ux,
                       const unsigned short* z, const float* hidden, const float* bh,
                       const float* rph_nrm, float* __restrict__ out){
  const int row = blockIdx.x, t = threadIdx.x;
  const int lane = t & 63, w = t >> 6;
  const size_t base = (size_t)row*1024;
  const float4 mh4 = bf2f4(((const ushort4*)(mh + base))[t]);
  float ss = dot4(mh4, mh4);
  #pragma unroll
  for (int o = 32; o; o >>= 1) ss += __shfl_down(ss,o);
  __shared__ float red[4];
  if (lane == 0) red[w] = ss;
  __syncthreads();
  const float nMh = fmaxf(sqrtf(red[0]+red[1]+red[2]+red[3]), EPSF);
  const float rnc = clipn(rph_nrm[row]);
  const float swh = tanhf(nMh/rnc*atanhf(rnc))/nMh;
  const float4 WhH = scal4(mh4, swh);
  const float4 Ux4 = bf2f4(((const ushort4*)(ux + base))[t]);
  const float4 bh4 = ((const float4*)bh)[t];
  const float4 ht = mob_add4(mob_add4(WhH, Ux4), bh4);
  const float4 h4 = ((const float4*)(hidden + base))[t];
  const float4 nh4 = make_float4(-h4.x, -h4.y, -h4.z, -h4.w);
  const float4 m4 = mob_add4(nh4, ht);
  const float4 z4 = bf2f4(((const ushort4*)(z + base))[t]);
  const float4 p4 = mob_pp4(m4, z4);
  const float4 o4 = mob_add4(h4, p4);
  ((float4*)(out + base))[t] = o4;
}

extern "C" void kernel_launch(void* const* d_in, const int* in_sizes, int n_in,
                              void* d_out, int out_size, void* d_ws, size_t ws_size,
                              hipStream_t stream) {
  (void)in_sizes; (void)n_in; (void)out_size; (void)ws_size;
  const float* hyp_x  = (const float*)d_in[0];
  const float* hidden = (const float*)d_in[1];
  const float* w_z = (const float*)d_in[2];
  const float* w_r = (const float*)d_in[3];
  const float* w_h = (const float*)d_in[4];
  const float* u_z = (const float*)d_in[5];
  const float* u_r = (const float*)d_in[6];
  // d_in[7] = u_h is unused by the reference (it uses u_r for h_tilde)
  const float* b_z = (const float*)d_in[8];
  const float* b_r = (const float*)d_in[9];
  const float* b_h = (const float*)d_in[10];
  float* out = (float*)d_out;

  const size_t NROW = 16384, MAT = NROW*1024;    // 16,777,216 elements
  // d_ws layout (bf16 everywhere): 4*32 MiB + 10 MiB + norms = 138.2 MiB
  unsigned short* hbf = (unsigned short*)d_ws;   // hidden bf16 -> later Mh output
  unsigned short* xbf = hbf + MAT;
  unsigned short* p0  = xbf + MAT;               // Mz_h -> z
  unsigned short* p3  = p0 + MAT;                // Mr_x -> Ux
  unsigned short* wzt = p3 + MAT;                // 1024x1024 bf16 each
  unsigned short* wrt = wzt + 1048576;
  unsigned short* wht = wrt + 1048576;
  unsigned short* uzt = wht + 1048576;
  unsigned short* urt = uzt + 1048576;
  float* h_n   = (float*)(urt + 1048576);
  float* x_n   = h_n + NROW;
  float* rph_n = x_n + NROW;
  // d_out as scratch for products dead before epi2: 64 MiB = 2 bf16 mats
  unsigned short* q0 = (unsigned short*)d_out;   // Mz_x -> rph
  unsigned short* q1 = q0 + MAT;                 // Mr_h

  cast_norm_k<<<dim3(16384), dim3(256), 0, stream>>>(hidden, hbf, h_n);
  cast_norm_k<<<dim3(16384), dim3(256), 0, stream>>>(hyp_x, xbf, x_n);

  dim3 wg(32, 32), wb(32, 8);
  wcast_k<<<wg, wb, 0, stream>>>(w_z, wzt);
  wcast_k<<<wg, wb, 0, stream>>>(w_r, wrt);
  wcast_k<<<wg, wb, 0, stream>>>(w_h, wht);
  wcast_k<<<wg, wb, 0, stream>>>(u_z, uzt);
  wcast_k<<<wg, wb, 0, stream>>>(u_r, urt);

  dim3 gg(4, 128);   // N/256 x M/128
  gemm_k<<<gg, dim3(512), 0, stream>>>(hbf, wzt, p0);   // Mz_h
  gemm_k<<<gg, dim3(512), 0, stream>>>(xbf, uzt, q0);   // Mz_x
  gemm_k<<<gg, dim3(512), 0, stream>>>(hbf, wrt, q1);   // Mr_h
  gemm_k<<<gg, dim3(512), 0, stream>>>(xbf, urt, p3);   // Mr_x

  epi1_k<<<dim3(16384), dim3(256), 0, stream>>>(p0, q0, q1, p3, hidden, b_z, b_r,
                                                h_n, x_n, rph_n);

  gemm_k<<<gg, dim3(512), 0, stream>>>(q0 /*rph*/, wht, hbf /*Mh*/);

  epi2_k<<<dim3(16384), dim3(256), 0, stream>>>(hbf, p3, p0, hidden, b_h, rph_n, out);
}

// Round 3
// 393.439 us; speedup vs baseline: 1.1518x; 1.1518x over previous
//
#include <hip/hip_runtime.h>
#include <stdint.h>

#define EPSF 1e-5f
#define MAXNF (1.0f - 1e-5f)

typedef __attribute__((ext_vector_type(8))) short short8;
typedef __attribute__((ext_vector_type(4))) float floatx4;

__device__ __forceinline__ unsigned short f2bf(float f){
  union { float f; uint32_t u; } v; v.f = f;
  return (unsigned short)((v.u + 0x7FFFu + ((v.u >> 16) & 1u)) >> 16);
}
__device__ __forceinline__ float bf2f(unsigned short s){
  union { uint32_t u; float f; } v; v.u = ((uint32_t)s) << 16;
  return v.f;
}
__device__ __forceinline__ float4 bf2f4(ushort4 s){
  return make_float4(bf2f(s.x), bf2f(s.y), bf2f(s.z), bf2f(s.w));
}
__device__ __forceinline__ ushort4 f2bf4(float4 f){
  ushort4 r; r.x=f2bf(f.x); r.y=f2bf(f.y); r.z=f2bf(f.z); r.w=f2bf(f.w); return r;
}

__device__ __forceinline__ void gload16(const void* g, void* l){
  __builtin_amdgcn_global_load_lds(
      (__attribute__((address_space(1))) void*)(uintptr_t)g,
      (__attribute__((address_space(3))) void*)l, 16, 0, 0);
}

// ---- fast transcendentals (v_exp_f32 / v_log_f32 / v_rcp_f32; ~1e-6 rel err,
// ---- vs 1.7e-3 output tolerance — library atanhf/tanhf were 106% VALUBusy) ----
__device__ __forceinline__ float fatanh(float x){           // x in [EPSF, MAXNF]
  return 0.5f * __logf(__fdividef(1.f + x, 1.f - x));
}
__device__ __forceinline__ float ftanh_pos(float x){        // x >= 0
  const float t = __expf(-2.f * x);
  return __fdividef(1.f - t, 1.f + t);
}
__device__ __forceinline__ float fsig(float x){
  return __fdividef(1.f, 1.f + __expf(-x));
}

// ---------------- cast to bf16 + per-row (1024) norm ----------------
__global__ void cast_norm_k(const float* __restrict__ X, unsigned short* __restrict__ Xbf,
                            float* __restrict__ nrm){
  const int row = blockIdx.x, t = threadIdx.x;
  const float4 v = ((const float4*)(X + (size_t)row*1024))[t];
  ((ushort4*)(Xbf + (size_t)row*1024))[t] = f2bf4(v);
  float ss = v.x*v.x + v.y*v.y + v.z*v.z + v.w*v.w;
  #pragma unroll
  for (int o = 32; o; o >>= 1) ss += __shfl_down(ss, o);
  __shared__ float red[4];
  const int lane = t & 63, w = t >> 6;
  if (lane == 0) red[w] = ss;
  __syncthreads();
  if (t == 0) nrm[row] = sqrtf(red[0] + red[1] + red[2] + red[3]);
}

// ---------------- weight transpose+cast: Wt[n][k] = bf16(W[k][n]) ----------------
__global__ void wcast_k(const float* __restrict__ W, unsigned short* __restrict__ Wt){
  __shared__ float tile[32][33];
  const int tx = threadIdx.x, ty = threadIdx.y;     // 32 x 8
  const int k0 = blockIdx.x * 32, n0 = blockIdx.y * 32;
  #pragma unroll
  for (int i = 0; i < 4; ++i)
    tile[ty + i*8][tx] = W[(size_t)(k0 + ty + i*8) * 1024 + n0 + tx];
  __syncthreads();
  #pragma unroll
  for (int i = 0; i < 4; ++i)
    Wt[(size_t)(n0 + ty + i*8) * 1024 + k0 + tx] = f2bf(tile[tx][ty + i*8]);
}

// ---------------- bf16 MFMA GEMM: C[m][n] = bf16( sum_k A[m][k] * Bt[n][k] ) ----------------
// BM=128, BN=256, BK=32, K=1024 fixed. lda/ldc parametrized (A may live in a
// [M][2048] buffer; C may be half of one). 512 threads = 8 waves (2x4), wave
// tile 64x64 = 4x4 frags of 16x16x32. Double-buffered LDS via global_load_lds
// (linear dest); XOR chunk swizzle (chunk ^= row&3) on global source AND on the
// ds_read address -> wave's ds_read_b128 spreads 8 accesses/bank (minimum).
#define GBM 128
#define GBN 256
#define GBK 32
#define GKD 1024

__global__ __launch_bounds__(512) void gemm_k(const unsigned short* __restrict__ A,
                                              const unsigned short* __restrict__ Bt,
                                              unsigned short* __restrict__ C,
                                              int lda, int ldc){
  __shared__ unsigned short smem[2*4096 + 2*8192];   // A: 2x(128x32), B: 2x(256x32)
  unsigned short* As = smem;
  unsigned short* Bs = smem + 2*4096;
  const int tid = threadIdx.x;
  const int lane = tid & 63, w = tid >> 6;
  const int wr = w >> 2, wc = w & 3;
  const int lr = lane & 15, kg = lane >> 4;
  const int row0 = blockIdx.y * GBM, col0 = blockIdx.x * GBN;

  int aoff[4], boff[4];
  #pragma unroll
  for (int a = 0; a < 4; ++a){
    const int r = wr*64 + a*16 + lr;
    aoff[a] = r*32 + ((kg ^ (r & 3)) << 3);
  }
  #pragma unroll
  for (int b = 0; b < 4; ++b){
    const int r = wc*64 + b*16 + lr;
    boff[b] = r*32 + ((kg ^ (r & 3)) << 3);
  }

  floatx4 acc[4][4] = {};

  auto stage = [&](int buf, int kt){
    {
      const int flat = tid;                       // 512 chunks for A tile
      const int r = flat >> 2, cp = flat & 3, c = cp ^ (r & 3);
      gload16(A + (size_t)(row0 + r)*lda + kt*GBK + c*8, As + buf*4096 + flat*8);
    }
    #pragma unroll
    for (int i = 0; i < 2; ++i){                  // 1024 chunks for B tile
      const int flat = i*512 + tid;
      const int r = flat >> 2, cp = flat & 3, c = cp ^ (r & 3);
      gload16(Bt + (size_t)(col0 + r)*GKD + kt*GBK + c*8, Bs + buf*8192 + flat*8);
    }
  };

  stage(0, 0);
  __syncthreads();
  int cur = 0;
  for (int kt = 0; kt < GKD/GBK; ++kt){
    if (kt + 1 < GKD/GBK) stage(cur ^ 1, kt + 1);
    const unsigned short* as = As + cur*4096;
    const unsigned short* bs = Bs + cur*8192;
    short8 af[4], bfv[4];
    #pragma unroll
    for (int a = 0; a < 4; ++a) af[a] = *(const short8*)(as + aoff[a]);
    #pragma unroll
    for (int b = 0; b < 4; ++b) bfv[b] = *(const short8*)(bs + boff[b]);
    #pragma unroll
    for (int a = 0; a < 4; ++a)
      #pragma unroll
      for (int b = 0; b < 4; ++b)
        acc[a][b] = __builtin_amdgcn_mfma_f32_16x16x32_bf16(af[a], bfv[b], acc[a][b], 0, 0, 0);
    __syncthreads();
    cur ^= 1;
  }

  const int crow0 = row0 + wr*64;
  const int ccol = col0 + wc*64 + lr;
  #pragma unroll
  for (int a = 0; a < 4; ++a){
    #pragma unroll
    for (int j = 0; j < 4; ++j){
      const int r = crow0 + a*16 + kg*4 + j;
      unsigned short* cp = C + (size_t)r*ldc + ccol;
      #pragma unroll
      for (int b = 0; b < 4; ++b) cp[b*16] = f2bf(acc[a][b][j]);
    }
  }
}

// ---------------- per-ball Mobius helpers (thread t owns ball t) ----------------
__device__ __forceinline__ float dot4(const float4 a, const float4 b){
  return a.x*b.x + a.y*b.y + a.z*b.z + a.w*b.w;
}
__device__ __forceinline__ float4 scal4(const float4 a, float s){
  return make_float4(a.x*s, a.y*s, a.z*s, a.w*s);
}
__device__ __forceinline__ float clipn(float n){ return fminf(fmaxf(n, EPSF), MAXNF); }

__device__ __forceinline__ float4 mob_add4(const float4 u, const float4 v){
  const float uv = dot4(u,v), uu = dot4(u,u), vv = dot4(v,v);
  const float cu = 1.f + 2.f*uv + vv, cv = 1.f - uu;
  const float inv = __fdividef(1.f, fmaxf(1.f + 2.f*uv + uu*vv, EPSF));
  return make_float4((cu*u.x + cv*v.x)*inv, (cu*u.y + cv*v.y)*inv,
                     (cu*u.z + cv*v.z)*inv, (cu*u.w + cv*v.w)*inv);
}

__device__ __forceinline__ float4 logmap_sig4(const float4 y){
  const float n = sqrtf(dot4(y,y));
  const float nc = clipn(n);
  const float s = __fdividef(fatanh(nc), nc);
  return make_float4(fsig(s*y.x), fsig(s*y.y), fsig(s*y.z), fsig(s*y.w));
}

__device__ __forceinline__ float4 mob_pp4(const float4 x, const float4 u){
  const float4 ux = make_float4(u.x*x.x, u.y*x.y, u.z*x.z, u.w*x.w);
  const float xn = clipn(sqrtf(dot4(x,x)));
  const float uxn = fmaxf(sqrtf(dot4(ux,ux)), EPSF);
  const float s = __fdividef(ftanh_pos(__fdividef(uxn, xn) * fatanh(xn)), uxn);
  return scal4(ux, s);
}

// ---------------- epilogue 1 ----------------
// C1 = [M][2048] bf16: cols 0-1023 Mz_h -> z ; cols 1024-2047 Mr_h -> Ux
// C2 = [M][2048] bf16 (d_out):  cols 0-1023 Mz_x -> rph ; cols 1024-2047 Mr_x (dead)
__global__ void epi1_k(unsigned short* C1, unsigned short* C2,
                       const float* hidden, const float* bz, const float* br,
                       const float* h_nrm, const float* x_nrm, float* rph_nrm){
  const int row = blockIdx.x, t = threadIdx.x;
  const int lane = t & 63, w = t >> 6;
  const size_t b2 = (size_t)row*2048;
  const float4 mzh  = bf2f4(((const ushort4*)(C1 + b2))[t]);
  const float4 mrh4 = bf2f4(((const ushort4*)(C1 + b2))[256 + t]);
  const float4 mzx4 = bf2f4(((const ushort4*)(C2 + b2))[t]);
  const float4 mrx4 = bf2f4(((const ushort4*)(C2 + b2))[256 + t]);
  float s0 = dot4(mzh,mzh), s1 = dot4(mzx4,mzx4), s2 = dot4(mrh4,mrh4), s3 = dot4(mrx4,mrx4);
  #pragma unroll
  for (int o = 32; o; o >>= 1){
    s0 += __shfl_down(s0,o); s1 += __shfl_down(s1,o);
    s2 += __shfl_down(s2,o); s3 += __shfl_down(s3,o);
  }
  __shared__ float red[4][4];
  if (lane == 0){ red[w][0]=s0; red[w][1]=s1; red[w][2]=s2; red[w][3]=s3; }
  __syncthreads();
  const float nMzh = fmaxf(sqrtf(red[0][0]+red[1][0]+red[2][0]+red[3][0]), EPSF);
  const float nMzx = fmaxf(sqrtf(red[0][1]+red[1][1]+red[2][1]+red[3][1]), EPSF);
  const float nMrh = fmaxf(sqrtf(red[0][2]+red[1][2]+red[2][2]+red[3][2]), EPSF);
  const float nMrx = fmaxf(sqrtf(red[0][3]+red[1][3]+red[2][3]+red[3][3]), EPSF);
  const float hnc = clipn(h_nrm[row]), xnc = clipn(x_nrm[row]);
  const float atH = fatanh(hnc), atX = fatanh(xnc);
  const float swz = __fdividef(ftanh_pos(__fdividef(nMzh, hnc)*atH), nMzh);
  const float suz = __fdividef(ftanh_pos(__fdividef(nMzx, xnc)*atX), nMzx);
  const float swr = __fdividef(ftanh_pos(__fdividef(nMrh, hnc)*atH), nMrh);
  const float sur = __fdividef(ftanh_pos(__fdividef(nMrx, xnc)*atX), nMrx);
  const float4 bz4 = ((const float4*)bz)[t];
  const float4 br4 = ((const float4*)br)[t];
  const float4 z4 = logmap_sig4(mob_add4(mob_add4(scal4(mzh,swz), scal4(mzx4,suz)), bz4));
  const float4 UxR = scal4(mrx4, sur);
  const float4 r4 = logmap_sig4(mob_add4(mob_add4(scal4(mrh4,swr), UxR), br4));
  ((ushort4*)(C1 + b2))[t]       = f2bf4(z4);    // z over Mz_h (same thread)
  ((ushort4*)(C1 + b2))[256 + t] = f2bf4(UxR);   // Ux over Mr_h (same thread)
  const float4 h4 = ((const float4*)(hidden + (size_t)row*1024))[t];
  const float4 rph = mob_pp4(h4, r4);
  ((ushort4*)(C2 + b2))[t] = f2bf4(rph);         // rph over Mz_x (same thread)
  float sr = dot4(rph, rph);
  #pragma unroll
  for (int o = 32; o; o >>= 1) sr += __shfl_down(sr,o);
  __syncthreads();
  if (lane == 0) red[w][0] = sr;
  __syncthreads();
  if (t == 0) rph_nrm[row] = sqrtf(red[0][0]+red[1][0]+red[2][0]+red[3][0]);
}

// ---------------- epilogue 2: h_tilde, final new_h ----------------
__global__ void epi2_k(const unsigned short* mh, const unsigned short* C1,
                       const float* hidden, const float* bh,
                       const float* rph_nrm, float* __restrict__ out){
  const int row = blockIdx.x, t = threadIdx.x;
  const int lane = t & 63, w = t >> 6;
  const size_t base = (size_t)row*1024, b2 = (size_t)row*2048;
  const float4 mh4 = bf2f4(((const ushort4*)(mh + base))[t]);
  float ss = dot4(mh4, mh4);
  #pragma unroll
  for (int o = 32; o; o >>= 1) ss += __shfl_down(ss,o);
  __shared__ float red[4];
  if (lane == 0) red[w] = ss;
  __syncthreads();
  const float nMh = fmaxf(sqrtf(red[0]+red[1]+red[2]+red[3]), EPSF);
  const float rnc = clipn(rph_nrm[row]);
  const float swh = __fdividef(ftanh_pos(__fdividef(nMh, rnc)*fatanh(rnc)), nMh);
  const float4 WhH = scal4(mh4, swh);
  const float4 Ux4 = bf2f4(((const ushort4*)(C1 + b2))[256 + t]);
  const float4 bh4 = ((const float4*)bh)[t];
  const float4 ht = mob_add4(mob_add4(WhH, Ux4), bh4);
  const float4 h4 = ((const float4*)(hidden + base))[t];
  const float4 nh4 = make_float4(-h4.x, -h4.y, -h4.z, -h4.w);
  const float4 m4 = mob_add4(nh4, ht);
  const float4 z4 = bf2f4(((const ushort4*)(C1 + b2))[t]);
  const float4 p4 = mob_pp4(m4, z4);
  const float4 o4 = mob_add4(h4, p4);
  ((float4*)(out + base))[t] = o4;
}

extern "C" void kernel_launch(void* const* d_in, const int* in_sizes, int n_in,
                              void* d_out, int out_size, void* d_ws, size_t ws_size,
                              hipStream_t stream) {
  (void)in_sizes; (void)n_in; (void)out_size; (void)ws_size;
  const float* hyp_x  = (const float*)d_in[0];
  const float* hidden = (const float*)d_in[1];
  const float* w_z = (const float*)d_in[2];
  const float* w_r = (const float*)d_in[3];
  const float* w_h = (const float*)d_in[4];
  const float* u_z = (const float*)d_in[5];
  const float* u_r = (const float*)d_in[6];
  // d_in[7] = u_h unused by the reference (it uses u_r for h_tilde)
  const float* b_z = (const float*)d_in[8];
  const float* b_r = (const float*)d_in[9];
  const float* b_h = (const float*)d_in[10];
  float* out = (float*)d_out;

  const size_t NROW = 16384, MAT = NROW*1024;
  // ws layout (144.5 MiB): hbf 32 + xbf 32 + C1 64 + weights 10 + norms
  unsigned short* hbf = (unsigned short*)d_ws;   // hidden bf16 -> later Mh
  unsigned short* xbf = hbf + MAT;
  unsigned short* C1  = xbf + MAT;               // [M][2048]: Mz_h|Mr_h -> z|Ux
  unsigned short* wzr = C1 + 2*MAT;              // [2048][1024]: wzt rows 0-1023, wrt rows 1024-2047
  unsigned short* uzr = wzr + 2*1048576;
  unsigned short* wht = uzr + 2*1048576;
  float* h_n   = (float*)(wht + 1048576);
  float* x_n   = h_n + NROW;
  float* rph_n = x_n + NROW;
  // d_out as scratch: C2 = [M][2048] bf16 (exactly 64 MiB): Mz_x|Mr_x -> rph|dead
  unsigned short* C2 = (unsigned short*)d_out;

  cast_norm_k<<<dim3(16384), dim3(256), 0, stream>>>(hidden, hbf, h_n);
  cast_norm_k<<<dim3(16384), dim3(256), 0, stream>>>(hyp_x, xbf, x_n);

  dim3 wg(32, 32), wb(32, 8);
  wcast_k<<<wg, wb, 0, stream>>>(w_z, wzr);
  wcast_k<<<wg, wb, 0, stream>>>(w_r, wzr + 1048576);
  wcast_k<<<wg, wb, 0, stream>>>(u_z, uzr);
  wcast_k<<<wg, wb, 0, stream>>>(u_r, uzr + 1048576);
  wcast_k<<<wg, wb, 0, stream>>>(w_h, wht);

  gemm_k<<<dim3(8,128), dim3(512), 0, stream>>>(hbf, wzr, C1, 1024, 2048); // Mz_h|Mr_h
  gemm_k<<<dim3(8,128), dim3(512), 0, stream>>>(xbf, uzr, C2, 1024, 2048); // Mz_x|Mr_x

  epi1_k<<<dim3(16384), dim3(256), 0, stream>>>(C1, C2, hidden, b_z, b_r,
                                                h_n, x_n, rph_n);

  gemm_k<<<dim3(4,128), dim3(512), 0, stream>>>(C2 /*rph, lda=2048*/, wht,
                                                hbf /*Mh*/, 2048, 1024);

  epi2_k<<<dim3(16384), dim3(256), 0, stream>>>(hbf, C1, hidden, b_h, rph_n, out);
}

// Round 4
// 374.559 us; speedup vs baseline: 1.2099x; 1.0504x over previous
//
#include <hip/hip_runtime.h>
#include <stdint.h>

#define EPSF 1e-5f
#define MAXNF (1.0f - 1e-5f)

typedef __attribute__((ext_vector_type(8))) short short8;
typedef __attribute__((ext_vector_type(4))) float floatx4;

__device__ __forceinline__ unsigned short f2bf(float f){
  union { float f; uint32_t u; } v; v.f = f;
  return (unsigned short)((v.u + 0x7FFFu + ((v.u >> 16) & 1u)) >> 16);
}
__device__ __forceinline__ float bf2f(unsigned short s){
  union { uint32_t u; float f; } v; v.u = ((uint32_t)s) << 16;
  return v.f;
}
__device__ __forceinline__ float4 bf2f4(ushort4 s){
  return make_float4(bf2f(s.x), bf2f(s.y), bf2f(s.z), bf2f(s.w));
}
// HW packed f32->bf16 (RNE): 1 inst per 2 elements
__device__ __forceinline__ uint32_t cvtpk(float lo, float hi){
  uint32_t r; asm("v_cvt_pk_bf16_f32 %0, %1, %2" : "=v"(r) : "v"(lo), "v"(hi));
  return r;
}
__device__ __forceinline__ void store_bf4(unsigned short* p, float4 v){
  uint2 r; r.x = cvtpk(v.x, v.y); r.y = cvtpk(v.z, v.w);
  *(uint2*)p = r;
}
__device__ __forceinline__ float fsqrt(float x){ return __builtin_amdgcn_sqrtf(x); }

__device__ __forceinline__ void gload16(const void* g, void* l){
  __builtin_amdgcn_global_load_lds(
      (__attribute__((address_space(1))) void*)(uintptr_t)g,
      (__attribute__((address_space(3))) void*)l, 16, 0, 0);
}

// ---- fast transcendentals (v_exp_f32 / v_log_f32 / v_rcp_f32; ~1e-6 rel err) ----
__device__ __forceinline__ float fatanh(float x){           // x in [EPSF, MAXNF]
  return 0.5f * __logf(__fdividef(1.f + x, 1.f - x));
}
__device__ __forceinline__ float ftanh_pos(float x){        // x >= 0
  const float t = __expf(-2.f * x);
  return __fdividef(1.f - t, 1.f + t);
}
__device__ __forceinline__ float fsig(float x){
  return __fdividef(1.f, 1.f + __expf(-x));
}

// ---------------- cast to bf16 + per-row (1024) norm ----------------
__global__ __launch_bounds__(256, 4) void cast_norm_k(const float* __restrict__ X,
                                                      unsigned short* __restrict__ Xbf,
                                                      float* __restrict__ nrm){
  const int row = blockIdx.x, t = threadIdx.x;
  const float4 v = ((const float4*)(X + (size_t)row*1024))[t];
  store_bf4(Xbf + (size_t)row*1024 + 4*t, v);
  float ss = v.x*v.x + v.y*v.y + v.z*v.z + v.w*v.w;
  #pragma unroll
  for (int o = 32; o; o >>= 1) ss += __shfl_down(ss, o);
  __shared__ float red[4];
  const int lane = t & 63, w = t >> 6;
  if (lane == 0) red[w] = ss;
  __syncthreads();
  if (t == 0) nrm[row] = fsqrt(red[0] + red[1] + red[2] + red[3]);
}

// ---------------- weight transpose+cast: Wt[n][k] = bf16(W[k][n]) ----------------
__global__ void wcast_k(const float* __restrict__ W, unsigned short* __restrict__ Wt){
  __shared__ float tile[32][33];
  const int tx = threadIdx.x, ty = threadIdx.y;     // 32 x 8
  const int k0 = blockIdx.x * 32, n0 = blockIdx.y * 32;
  #pragma unroll
  for (int i = 0; i < 4; ++i)
    tile[ty + i*8][tx] = W[(size_t)(k0 + ty + i*8) * 1024 + n0 + tx];
  __syncthreads();
  #pragma unroll
  for (int i = 0; i < 4; ++i)
    Wt[(size_t)(n0 + ty + i*8) * 1024 + k0 + tx] = f2bf(tile[tx][ty + i*8]);
}

// ---------------- bf16 MFMA GEMM: C[m][n] = bf16( sum_k A[m][k] * Bt[n][k] ) ----------------
// BM=128, BN=256, BK=32, K=1024 fixed. lda/ldc parametrized. 512 threads = 8
// waves (2x4), wave tile 64x64 = 4x4 frags of 16x16x32. Double-buffered LDS via
// global_load_lds (linear dest); XOR chunk swizzle (chunk ^= row&3) on global
// source AND ds_read address -> wave's ds_read_b128 spreads 8/bank (minimum).
#define GBM 128
#define GBN 256
#define GBK 32
#define GKD 1024

__global__ __launch_bounds__(512) void gemm_k(const unsigned short* __restrict__ A,
                                              const unsigned short* __restrict__ Bt,
                                              unsigned short* __restrict__ C,
                                              int lda, int ldc){
  __shared__ unsigned short smem[2*4096 + 2*8192];   // A: 2x(128x32), B: 2x(256x32)
  unsigned short* As = smem;
  unsigned short* Bs = smem + 2*4096;
  const int tid = threadIdx.x;
  const int lane = tid & 63, w = tid >> 6;
  const int wr = w >> 2, wc = w & 3;
  const int lr = lane & 15, kg = lane >> 4;
  const int row0 = blockIdx.y * GBM, col0 = blockIdx.x * GBN;

  int aoff[4], boff[4];
  #pragma unroll
  for (int a = 0; a < 4; ++a){
    const int r = wr*64 + a*16 + lr;
    aoff[a] = r*32 + ((kg ^ (r & 3)) << 3);
  }
  #pragma unroll
  for (int b = 0; b < 4; ++b){
    const int r = wc*64 + b*16 + lr;
    boff[b] = r*32 + ((kg ^ (r & 3)) << 3);
  }

  floatx4 acc[4][4] = {};

  auto stage = [&](int buf, int kt){
    {
      const int flat = tid;                       // 512 chunks for A tile
      const int r = flat >> 2, cp = flat & 3, c = cp ^ (r & 3);
      gload16(A + (size_t)(row0 + r)*lda + kt*GBK + c*8, As + buf*4096 + flat*8);
    }
    #pragma unroll
    for (int i = 0; i < 2; ++i){                  // 1024 chunks for B tile
      const int flat = i*512 + tid;
      const int r = flat >> 2, cp = flat & 3, c = cp ^ (r & 3);
      gload16(Bt + (size_t)(col0 + r)*GKD + kt*GBK + c*8, Bs + buf*8192 + flat*8);
    }
  };

  stage(0, 0);
  __syncthreads();
  int cur = 0;
  for (int kt = 0; kt < GKD/GBK; ++kt){
    if (kt + 1 < GKD/GBK) stage(cur ^ 1, kt + 1);
    const unsigned short* as = As + cur*4096;
    const unsigned short* bs = Bs + cur*8192;
    short8 af[4], bfv[4];
    #pragma unroll
    for (int a = 0; a < 4; ++a) af[a] = *(const short8*)(as + aoff[a]);
    #pragma unroll
    for (int b = 0; b < 4; ++b) bfv[b] = *(const short8*)(bs + boff[b]);
    #pragma unroll
    for (int a = 0; a < 4; ++a)
      #pragma unroll
      for (int b = 0; b < 4; ++b)
        acc[a][b] = __builtin_amdgcn_mfma_f32_16x16x32_bf16(af[a], bfv[b], acc[a][b], 0, 0, 0);
    __syncthreads();
    cur ^= 1;
  }

  const int crow0 = row0 + wr*64;
  const int ccol = col0 + wc*64 + lr;
  #pragma unroll
  for (int a = 0; a < 4; ++a){
    #pragma unroll
    for (int j = 0; j < 4; ++j){
      const int r = crow0 + a*16 + kg*4 + j;
      unsigned short* cp = C + (size_t)r*ldc + ccol;
      #pragma unroll
      for (int b = 0; b < 4; ++b) cp[b*16] = f2bf(acc[a][b][j]);
    }
  }
}

// ---------------- per-ball Mobius helpers (thread t owns ball t) ----------------
__device__ __forceinline__ float dot4(const float4 a, const float4 b){
  return a.x*b.x + a.y*b.y + a.z*b.z + a.w*b.w;
}
__device__ __forceinline__ float4 scal4(const float4 a, float s){
  return make_float4(a.x*s, a.y*s, a.z*s, a.w*s);
}
__device__ __forceinline__ float clipn(float n){ return fminf(fmaxf(n, EPSF), MAXNF); }

__device__ __forceinline__ float4 mob_add4(const float4 u, const float4 v){
  const float uv = dot4(u,v), uu = dot4(u,u), vv = dot4(v,v);
  const float cu = 1.f + 2.f*uv + vv, cv = 1.f - uu;
  const float inv = __fdividef(1.f, fmaxf(1.f + 2.f*uv + uu*vv, EPSF));
  return make_float4((cu*u.x + cv*v.x)*inv, (cu*u.y + cv*v.y)*inv,
                     (cu*u.z + cv*v.z)*inv, (cu*u.w + cv*v.w)*inv);
}

__device__ __forceinline__ float4 logmap_sig4(const float4 y){
  const float n = fsqrt(dot4(y,y));
  const float nc = clipn(n);
  const float s = __fdividef(fatanh(nc), nc);
  return make_float4(fsig(s*y.x), fsig(s*y.y), fsig(s*y.z), fsig(s*y.w));
}

__device__ __forceinline__ float4 mob_pp4(const float4 x, const float4 u){
  const float4 ux = make_float4(u.x*x.x, u.y*x.y, u.z*x.z, u.w*x.w);
  const float xn = clipn(fsqrt(dot4(x,x)));
  const float uxn = fmaxf(fsqrt(dot4(ux,ux)), EPSF);
  const float s = __fdividef(ftanh_pos(__fdividef(uxn, xn) * fatanh(xn)), uxn);
  return scal4(ux, s);
}

// ---------------- epilogue 1 ----------------
// C1 = [M][2048] bf16: cols 0-1023 Mz_h -> z ; cols 1024-2047 Mr_h -> Ux
// C2 = [M][2048] bf16 (d_out):  cols 0-1023 Mz_x -> rph ; cols 1024-2047 Mr_x (dead)
__global__ __launch_bounds__(256, 4) void epi1_k(unsigned short* C1, unsigned short* C2,
                       const float* hidden, const float* bz, const float* br,
                       const float* h_nrm, const float* x_nrm, float* rph_nrm){
  const int row = blockIdx.x, t = threadIdx.x;
  const int lane = t & 63, w = t >> 6;
  const size_t b2 = (size_t)row*2048;
  const float4 mzh  = bf2f4(((const ushort4*)(C1 + b2))[t]);
  const float4 mrh4 = bf2f4(((const ushort4*)(C1 + b2))[256 + t]);
  const float4 mzx4 = bf2f4(((const ushort4*)(C2 + b2))[t]);
  const float4 mrx4 = bf2f4(((const ushort4*)(C2 + b2))[256 + t]);
  float s0 = dot4(mzh,mzh), s1 = dot4(mzx4,mzx4), s2 = dot4(mrh4,mrh4), s3 = dot4(mrx4,mrx4);
  #pragma unroll
  for (int o = 32; o; o >>= 1){
    s0 += __shfl_down(s0,o); s1 += __shfl_down(s1,o);
    s2 += __shfl_down(s2,o); s3 += __shfl_down(s3,o);
  }
  __shared__ float red[4][4];
  if (lane == 0){ red[w][0]=s0; red[w][1]=s1; red[w][2]=s2; red[w][3]=s3; }
  __syncthreads();
  const float nMzh = fmaxf(fsqrt(red[0][0]+red[1][0]+red[2][0]+red[3][0]), EPSF);
  const float nMzx = fmaxf(fsqrt(red[0][1]+red[1][1]+red[2][1]+red[3][1]), EPSF);
  const float nMrh = fmaxf(fsqrt(red[0][2]+red[1][2]+red[2][2]+red[3][2]), EPSF);
  const float nMrx = fmaxf(fsqrt(red[0][3]+red[1][3]+red[2][3]+red[3][3]), EPSF);
  const float hnc = clipn(h_nrm[row]), xnc = clipn(x_nrm[row]);
  const float atH = fatanh(hnc), atX = fatanh(xnc);
  const float swz = __fdividef(ftanh_pos(__fdividef(nMzh, hnc)*atH), nMzh);
  const float suz = __fdividef(ftanh_pos(__fdividef(nMzx, xnc)*atX), nMzx);
  const float swr = __fdividef(ftanh_pos(__fdividef(nMrh, hnc)*atH), nMrh);
  const float sur = __fdividef(ftanh_pos(__fdividef(nMrx, xnc)*atX), nMrx);
  const float4 bz4 = ((const float4*)bz)[t];
  const float4 br4 = ((const float4*)br)[t];
  const float4 z4 = logmap_sig4(mob_add4(mob_add4(scal4(mzh,swz), scal4(mzx4,suz)), bz4));
  const float4 UxR = scal4(mrx4, sur);
  const float4 r4 = logmap_sig4(mob_add4(mob_add4(scal4(mrh4,swr), UxR), br4));
  store_bf4(C1 + b2 + 4*t, z4);           // z over Mz_h (same thread)
  store_bf4(C1 + b2 + 1024 + 4*t, UxR);   // Ux over Mr_h (same thread)
  const float4 h4 = ((const float4*)(hidden + (size_t)row*1024))[t];
  const float4 rph = mob_pp4(h4, r4);
  store_bf4(C2 + b2 + 4*t, rph);          // rph over Mz_x (same thread)
  float sr = dot4(rph, rph);
  #pragma unroll
  for (int o = 32; o; o >>= 1) sr += __shfl_down(sr,o);
  __syncthreads();
  if (lane == 0) red[w][0] = sr;
  __syncthreads();
  if (t == 0) rph_nrm[row] = fsqrt(red[0][0]+red[1][0]+red[2][0]+red[3][0]);
}

// ---------------- epilogue 2: h_tilde, final new_h ----------------
__global__ __launch_bounds__(256, 4) void epi2_k(const unsigned short* mh,
                       const unsigned short* C1,
                       const float* hidden, const float* bh,
                       const float* rph_nrm, float* __restrict__ out){
  const int row = blockIdx.x, t = threadIdx.x;
  const int lane = t & 63, w = t >> 6;
  const size_t base = (size_t)row*1024, b2 = (size_t)row*2048;
  const float4 mh4 = bf2f4(((const ushort4*)(mh + base))[t]);
  float ss = dot4(mh4, mh4);
  #pragma unroll
  for (int o = 32; o; o >>= 1) ss += __shfl_down(ss,o);
  __shared__ float red[4];
  if (lane == 0) red[w] = ss;
  __syncthreads();
  const float nMh = fmaxf(fsqrt(red[0]+red[1]+red[2]+red[3]), EPSF);
  const float rnc = clipn(rph_nrm[row]);
  const float swh = __fdividef(ftanh_pos(__fdividef(nMh, rnc)*fatanh(rnc)), nMh);
  const float4 WhH = scal4(mh4, swh);
  const float4 Ux4 = bf2f4(((const ushort4*)(C1 + b2))[256 + t]);
  const float4 bh4 = ((const float4*)bh)[t];
  const float4 ht = mob_add4(mob_add4(WhH, Ux4), bh4);
  const float4 h4 = ((const float4*)(hidden + base))[t];
  const float4 nh4 = make_float4(-h4.x, -h4.y, -h4.z, -h4.w);
  const float4 m4 = mob_add4(nh4, ht);
  const float4 z4 = bf2f4(((const ushort4*)(C1 + b2))[t]);
  const float4 p4 = mob_pp4(m4, z4);
  const float4 o4 = mob_add4(h4, p4);
  ((float4*)(out + base))[t] = o4;
}

extern "C" void kernel_launch(void* const* d_in, const int* in_sizes, int n_in,
                              void* d_out, int out_size, void* d_ws, size_t ws_size,
                              hipStream_t stream) {
  (void)in_sizes; (void)n_in; (void)out_size; (void)ws_size;
  const float* hyp_x  = (const float*)d_in[0];
  const float* hidden = (const float*)d_in[1];
  const float* w_z = (const float*)d_in[2];
  const float* w_r = (const float*)d_in[3];
  const float* w_h = (const float*)d_in[4];
  const float* u_z = (const float*)d_in[5];
  const float* u_r = (const float*)d_in[6];
  // d_in[7] = u_h unused by the reference (it uses u_r for h_tilde)
  const float* b_z = (const float*)d_in[8];
  const float* b_r = (const float*)d_in[9];
  const float* b_h = (const float*)d_in[10];
  float* out = (float*)d_out;

  const size_t NROW = 16384, MAT = NROW*1024;
  // ws layout (144.5 MiB): hbf 32 + xbf 32 + C1 64 + weights 10 + norms
  unsigned short* hbf = (unsigned short*)d_ws;   // hidden bf16 -> later Mh
  unsigned short* xbf = hbf + MAT;
  unsigned short* C1  = xbf + MAT;               // [M][2048]: Mz_h|Mr_h -> z|Ux
  unsigned short* wzr = C1 + 2*MAT;              // [2048][1024]: wzt | wrt
  unsigned short* uzr = wzr + 2*1048576;
  unsigned short* wht = uzr + 2*1048576;
  float* h_n   = (float*)(wht + 1048576);
  float* x_n   = h_n + NROW;
  float* rph_n = x_n + NROW;
  // d_out as scratch: C2 = [M][2048] bf16 (exactly 64 MiB): Mz_x|Mr_x -> rph|dead
  unsigned short* C2 = (unsigned short*)d_out;

  cast_norm_k<<<dim3(16384), dim3(256), 0, stream>>>(hidden, hbf, h_n);
  cast_norm_k<<<dim3(16384), dim3(256), 0, stream>>>(hyp_x, xbf, x_n);

  dim3 wg(32, 32), wb(32, 8);
  wcast_k<<<wg, wb, 0, stream>>>(w_z, wzr);
  wcast_k<<<wg, wb, 0, stream>>>(w_r, wzr + 1048576);
  wcast_k<<<wg, wb, 0, stream>>>(u_z, uzr);
  wcast_k<<<wg, wb, 0, stream>>>(u_r, uzr + 1048576);
  wcast_k<<<wg, wb, 0, stream>>>(w_h, wht);

  gemm_k<<<dim3(8,128), dim3(512), 0, stream>>>(hbf, wzr, C1, 1024, 2048); // Mz_h|Mr_h
  gemm_k<<<dim3(8,128), dim3(512), 0, stream>>>(xbf, uzr, C2, 1024, 2048); // Mz_x|Mr_x

  epi1_k<<<dim3(16384), dim3(256), 0, stream>>>(C1, C2, hidden, b_z, b_r,
                                                h_n, x_n, rph_n);

  gemm_k<<<dim3(4,128), dim3(512), 0, stream>>>(C2 /*rph, lda=2048*/, wht,
                                                hbf /*Mh*/, 2048, 1024);

  epi2_k<<<dim3(16384), dim3(256), 0, stream>>>(hbf, C1, hidden, b_h, rph_n, out);
}

// Round 5
// 347.414 us; speedup vs baseline: 1.3044x; 1.0781x over previous
//
#include <hip/hip_runtime.h>
#include <stdint.h>

#define EPSF 1e-5f
#define MAXNF (1.0f - 1e-5f)

typedef __attribute__((ext_vector_type(8))) short short8;
typedef __attribute__((ext_vector_type(4))) float floatx4;

__device__ __forceinline__ unsigned short f2bf(float f){
  union { float f; uint32_t u; } v; v.f = f;
  return (unsigned short)((v.u + 0x7FFFu + ((v.u >> 16) & 1u)) >> 16);
}
__device__ __forceinline__ float bf_lo(uint32_t u){
  union { uint32_t u; float f; } v; v.u = u << 16; return v.f;
}
__device__ __forceinline__ float bf_hi(uint32_t u){
  union { uint32_t u; float f; } v; v.u = u & 0xffff0000u; return v.f;
}
// HW packed f32->bf16 (RNE)
__device__ __forceinline__ uint32_t cvtpk(float lo, float hi){
  uint32_t r; asm("v_cvt_pk_bf16_f32 %0, %1, %2" : "=v"(r) : "v"(lo), "v"(hi));
  return r;
}
__device__ __forceinline__ float fsqrt(float x){ return __builtin_amdgcn_sqrtf(x); }

// ball b (4 bf16) load/store at 8B granularity — stride-64-ball interleave keeps
// lane j at byte 8j: perfectly coalesced.
__device__ __forceinline__ float4 ld_ball(const unsigned short* rowp, int b){
  const uint2 u = *(const uint2*)(rowp + 4*b);
  return make_float4(bf_lo(u.x), bf_hi(u.x), bf_lo(u.y), bf_hi(u.y));
}
__device__ __forceinline__ void st_ball(unsigned short* rowp, int b, float4 f){
  uint2 u; u.x = cvtpk(f.x, f.y); u.y = cvtpk(f.z, f.w);
  *(uint2*)(rowp + 4*b) = u;
}

__device__ __forceinline__ void gload16(const void* g, void* l){
  __builtin_amdgcn_global_load_lds(
      (__attribute__((address_space(1))) void*)(uintptr_t)g,
      (__attribute__((address_space(3))) void*)l, 16, 0, 0);
}

// ---- fast transcendentals (v_exp/v_log/v_rcp; ~1e-6 rel err vs 1.7e-3 tol) ----
__device__ __forceinline__ float fatanh(float x){           // x in [EPSF, MAXNF]
  return 0.5f * __logf(__fdividef(1.f + x, 1.f - x));
}
__device__ __forceinline__ float ftanh_pos(float x){        // x >= 0
  const float t = __expf(-2.f * x);
  return __fdividef(1.f - t, 1.f + t);
}
__device__ __forceinline__ float fsig(float x){
  return __fdividef(1.f, 1.f + __expf(-x));
}

// full-wave (64) butterfly sum; result in all lanes
__device__ __forceinline__ float wsum(float v){
  #pragma unroll
  for (int o = 32; o; o >>= 1) v += __shfl_xor(v, o);
  return v;
}

// ---------------- per-ball Mobius helpers ----------------
__device__ __forceinline__ float dot4(const float4 a, const float4 b){
  return a.x*b.x + a.y*b.y + a.z*b.z + a.w*b.w;
}
__device__ __forceinline__ float4 scal4(const float4 a, float s){
  return make_float4(a.x*s, a.y*s, a.z*s, a.w*s);
}
__device__ __forceinline__ float clipn(float n){ return fminf(fmaxf(n, EPSF), MAXNF); }

__device__ __forceinline__ float4 mob_add4(const float4 u, const float4 v){
  const float uv = dot4(u,v), uu = dot4(u,u), vv = dot4(v,v);
  const float cu = 1.f + 2.f*uv + vv, cv = 1.f - uu;
  const float inv = __fdividef(1.f, fmaxf(1.f + 2.f*uv + uu*vv, EPSF));
  return make_float4((cu*u.x + cv*v.x)*inv, (cu*u.y + cv*v.y)*inv,
                     (cu*u.z + cv*v.z)*inv, (cu*u.w + cv*v.w)*inv);
}
__device__ __forceinline__ float4 logmap_sig4(const float4 y){
  const float nc = clipn(fsqrt(dot4(y,y)));
  const float s = __fdividef(fatanh(nc), nc);
  return make_float4(fsig(s*y.x), fsig(s*y.y), fsig(s*y.z), fsig(s*y.w));
}
__device__ __forceinline__ float4 mob_pp4(const float4 x, const float4 u){
  const float4 ux = make_float4(u.x*x.x, u.y*x.y, u.z*x.z, u.w*x.w);
  const float xn = clipn(fsqrt(dot4(x,x)));
  const float uxn = fmaxf(fsqrt(dot4(ux,ux)), EPSF);
  const float s = __fdividef(ftanh_pos(__fdividef(uxn, xn) * fatanh(xn)), uxn);
  return scal4(ux, s);
}

// ---------------- cast to bf16 + per-row norm (wave-per-row) ----------------
__global__ void cast_norm_k(const float* __restrict__ X, unsigned short* __restrict__ Xbf,
                            float* __restrict__ nrm){
  const int lane = threadIdx.x & 63;
  const int row  = blockIdx.x*4 + (threadIdx.x >> 6);
  const float4* xr = (const float4*)(X + (size_t)row*1024);
  unsigned short* br_ = Xbf + (size_t)row*1024;
  float ss = 0.f;
  #pragma unroll
  for (int i = 0; i < 4; ++i){
    const int b = lane + 64*i;
    const float4 v = xr[b];
    st_ball(br_, b, v);
    ss += dot4(v, v);
  }
  ss = wsum(ss);
  if (lane == 0) nrm[row] = fsqrt(ss);
}

// ---------------- weight transpose+cast: Wt[n][k] = bf16(W[k][n]) ----------------
__global__ void wcast_k(const float* __restrict__ W, unsigned short* __restrict__ Wt){
  __shared__ float tile[32][33];
  const int tx = threadIdx.x, ty = threadIdx.y;     // 32 x 8
  const int k0 = blockIdx.x * 32, n0 = blockIdx.y * 32;
  #pragma unroll
  for (int i = 0; i < 4; ++i)
    tile[ty + i*8][tx] = W[(size_t)(k0 + ty + i*8) * 1024 + n0 + tx];
  __syncthreads();
  #pragma unroll
  for (int i = 0; i < 4; ++i)
    Wt[(size_t)(n0 + ty + i*8) * 1024 + k0 + tx] = f2bf(tile[tx][ty + i*8]);
}

// ---------------- bf16 MFMA GEMM (unchanged from round 4) ----------------
#define GBM 128
#define GBN 256
#define GBK 32
#define GKD 1024

__global__ __launch_bounds__(512) void gemm_k(const unsigned short* __restrict__ A,
                                              const unsigned short* __restrict__ Bt,
                                              unsigned short* __restrict__ C,
                                              int lda, int ldc){
  __shared__ unsigned short smem[2*4096 + 2*8192];   // A: 2x(128x32), B: 2x(256x32)
  unsigned short* As = smem;
  unsigned short* Bs = smem + 2*4096;
  const int tid = threadIdx.x;
  const int lane = tid & 63, w = tid >> 6;
  const int wr = w >> 2, wc = w & 3;
  const int lr = lane & 15, kg = lane >> 4;
  const int row0 = blockIdx.y * GBM, col0 = blockIdx.x * GBN;

  int aoff[4], boff[4];
  #pragma unroll
  for (int a = 0; a < 4; ++a){
    const int r = wr*64 + a*16 + lr;
    aoff[a] = r*32 + ((kg ^ (r & 3)) << 3);
  }
  #pragma unroll
  for (int b = 0; b < 4; ++b){
    const int r = wc*64 + b*16 + lr;
    boff[b] = r*32 + ((kg ^ (r & 3)) << 3);
  }

  floatx4 acc[4][4] = {};

  auto stage = [&](int buf, int kt){
    {
      const int flat = tid;                       // 512 chunks for A tile
      const int r = flat >> 2, cp = flat & 3, c = cp ^ (r & 3);
      gload16(A + (size_t)(row0 + r)*lda + kt*GBK + c*8, As + buf*4096 + flat*8);
    }
    #pragma unroll
    for (int i = 0; i < 2; ++i){                  // 1024 chunks for B tile
      const int flat = i*512 + tid;
      const int r = flat >> 2, cp = flat & 3, c = cp ^ (r & 3);
      gload16(Bt + (size_t)(col0 + r)*GKD + kt*GBK + c*8, Bs + buf*8192 + flat*8);
    }
  };

  stage(0, 0);
  __syncthreads();
  int cur = 0;
  for (int kt = 0; kt < GKD/GBK; ++kt){
    if (kt + 1 < GKD/GBK) stage(cur ^ 1, kt + 1);
    const unsigned short* as = As + cur*4096;
    const unsigned short* bs = Bs + cur*8192;
    short8 af[4], bfv[4];
    #pragma unroll
    for (int a = 0; a < 4; ++a) af[a] = *(const short8*)(as + aoff[a]);
    #pragma unroll
    for (int b = 0; b < 4; ++b) bfv[b] = *(const short8*)(bs + boff[b]);
    #pragma unroll
    for (int a = 0; a < 4; ++a)
      #pragma unroll
      for (int b = 0; b < 4; ++b)
        acc[a][b] = __builtin_amdgcn_mfma_f32_16x16x32_bf16(af[a], bfv[b], acc[a][b], 0, 0, 0);
    __syncthreads();
    cur ^= 1;
  }

  const int crow0 = row0 + wr*64;
  const int ccol = col0 + wc*64 + lr;
  #pragma unroll
  for (int a = 0; a < 4; ++a){
    #pragma unroll
    for (int j = 0; j < 4; ++j){
      const int r = crow0 + a*16 + kg*4 + j;
      unsigned short* cp = C + (size_t)r*ldc + ccol;
      #pragma unroll
      for (int b = 0; b < 4; ++b) cp[b*16] = f2bf(acc[a][b][j]);
    }
  }
}

// ---------------- epilogue 1 (wave-per-row, lane owns balls lane+64i) ----------------
// C1 = [M][2048]: Mz_h|Mr_h -> z|Ux ;  C2 = [M][2048] (d_out): Mz_x|Mr_x -> rph|dead
__global__ __launch_bounds__(256) __attribute__((amdgpu_waves_per_eu(4,4)))
void epi1_k(unsigned short* C1, unsigned short* C2, const unsigned short* hbf,
            const float* bz, const float* br,
            const float* h_nrm, const float* x_nrm, float* rph_nrm){
  const int lane = threadIdx.x & 63;
  const int row  = blockIdx.x*4 + (threadIdx.x >> 6);
  unsigned short* c1lo = C1 + (size_t)row*2048;
  unsigned short* c1hi = c1lo + 1024;
  unsigned short* c2lo = C2 + (size_t)row*2048;
  unsigned short* c2hi = c2lo + 1024;
  const unsigned short* hr = hbf + (size_t)row*1024;

  float4 mzh[4], mrh[4], mzx[4], mrx[4];
  float s0 = 0.f, s1 = 0.f, s2 = 0.f, s3 = 0.f;
  #pragma unroll
  for (int i = 0; i < 4; ++i){
    const int b = lane + 64*i;
    mzh[i] = ld_ball(c1lo, b); mrh[i] = ld_ball(c1hi, b);
    mzx[i] = ld_ball(c2lo, b); mrx[i] = ld_ball(c2hi, b);
    s0 += dot4(mzh[i], mzh[i]); s1 += dot4(mzx[i], mzx[i]);
    s2 += dot4(mrh[i], mrh[i]); s3 += dot4(mrx[i], mrx[i]);
  }
  s0 = wsum(s0); s1 = wsum(s1); s2 = wsum(s2); s3 = wsum(s3);

  const float nMzh = fmaxf(fsqrt(s0), EPSF);
  const float nMzx = fmaxf(fsqrt(s1), EPSF);
  const float nMrh = fmaxf(fsqrt(s2), EPSF);
  const float nMrx = fmaxf(fsqrt(s3), EPSF);
  const float hnc = clipn(h_nrm[row]), xnc = clipn(x_nrm[row]);
  const float atH = fatanh(hnc), atX = fatanh(xnc);
  const float swz = __fdividef(ftanh_pos(__fdividef(nMzh, hnc)*atH), nMzh);
  const float suz = __fdividef(ftanh_pos(__fdividef(nMzx, xnc)*atX), nMzx);
  const float swr = __fdividef(ftanh_pos(__fdividef(nMrh, hnc)*atH), nMrh);
  const float sur = __fdividef(ftanh_pos(__fdividef(nMrx, xnc)*atX), nMrx);

  float sr = 0.f;
  #pragma unroll
  for (int i = 0; i < 4; ++i){
    const int b = lane + 64*i;
    const float4 bz4 = ((const float4*)bz)[b];
    const float4 br4 = ((const float4*)br)[b];
    const float4 z4  = logmap_sig4(mob_add4(mob_add4(scal4(mzh[i],swz), scal4(mzx[i],suz)), bz4));
    const float4 UxR = scal4(mrx[i], sur);
    const float4 r4  = logmap_sig4(mob_add4(mob_add4(scal4(mrh[i],swr), UxR), br4));
    st_ball(c1lo, b, z4);                        // z over Mz_h (same lane, same bytes)
    st_ball(c1hi, b, UxR);                       // Ux over Mr_h
    const float4 h4  = ld_ball(hr, b);
    const float4 rph = mob_pp4(h4, r4);
    st_ball(c2lo, b, rph);                       // rph over Mz_x
    sr += dot4(rph, rph);
  }
  sr = wsum(sr);
  if (lane == 0) rph_nrm[row] = fsqrt(sr);
}

// ---------------- epilogue 2 (wave-per-row): h_tilde, final new_h ----------------
// Mh lives in C2 hi half; out (fp32) overwrites all of C2 — safe: every Mh load
// feeds swh (computed before the first store) so loads complete first, and one
// wave owns the whole row (no cross-wave overlap).
__global__ __launch_bounds__(256) __attribute__((amdgpu_waves_per_eu(4,4)))
void epi2_k(const unsigned short* C1, const unsigned short* C2,
            const unsigned short* hbf, const float* bh,
            const float* rph_nrm, float* out){
  const int lane = threadIdx.x & 63;
  const int row  = blockIdx.x*4 + (threadIdx.x >> 6);
  const unsigned short* c1lo = C1 + (size_t)row*2048;
  const unsigned short* c1hi = c1lo + 1024;
  const unsigned short* c2hi = C2 + (size_t)row*2048 + 1024;
  const unsigned short* hr = hbf + (size_t)row*1024;
  float4* outr = (float4*)(out + (size_t)row*1024);

  float4 mh[4];
  float ss = 0.f;
  #pragma unroll
  for (int i = 0; i < 4; ++i){
    mh[i] = ld_ball(c2hi, lane + 64*i);
    ss += dot4(mh[i], mh[i]);
  }
  ss = wsum(ss);
  const float nMh = fmaxf(fsqrt(ss), EPSF);
  const float rnc = clipn(rph_nrm[row]);
  const float swh = __fdividef(ftanh_pos(__fdividef(nMh, rnc)*fatanh(rnc)), nMh);

  #pragma unroll
  for (int i = 0; i < 4; ++i){
    const int b = lane + 64*i;
    const float4 WhH = scal4(mh[i], swh);
    const float4 Ux4 = ld_ball(c1hi, b);
    const float4 bh4 = ((const float4*)bh)[b];
    const float4 ht  = mob_add4(mob_add4(WhH, Ux4), bh4);
    const float4 h4  = ld_ball(hr, b);
    const float4 nh4 = make_float4(-h4.x, -h4.y, -h4.z, -h4.w);
    const float4 m4  = mob_add4(nh4, ht);
    const float4 z4  = ld_ball(c1lo, b);
    const float4 p4  = mob_pp4(m4, z4);
    outr[b] = mob_add4(h4, p4);
  }
}

extern "C" void kernel_launch(void* const* d_in, const int* in_sizes, int n_in,
                              void* d_out, int out_size, void* d_ws, size_t ws_size,
                              hipStream_t stream) {
  (void)in_sizes; (void)n_in; (void)out_size; (void)ws_size;
  const float* hyp_x  = (const float*)d_in[0];
  const float* hidden = (const float*)d_in[1];
  const float* w_z = (const float*)d_in[2];
  const float* w_r = (const float*)d_in[3];
  const float* w_h = (const float*)d_in[4];
  const float* u_z = (const float*)d_in[5];
  const float* u_r = (const float*)d_in[6];
  // d_in[7] = u_h unused by the reference (it uses u_r for h_tilde)
  const float* b_z = (const float*)d_in[8];
  const float* b_r = (const float*)d_in[9];
  const float* b_h = (const float*)d_in[10];
  float* out = (float*)d_out;

  const size_t NROW = 16384, MAT = NROW*1024;
  // ws layout (144.5 MiB): hbf 32 + xbf 32 + C1 64 + weights 10 + norms
  unsigned short* hbf = (unsigned short*)d_ws;   // bf16(hidden) — stays live to the end
  unsigned short* xbf = hbf + MAT;
  unsigned short* C1  = xbf + MAT;               // [M][2048]: Mz_h|Mr_h -> z|Ux
  unsigned short* wzr = C1 + 2*MAT;              // [2048][1024]: wzt | wrt
  unsigned short* uzr = wzr + 2*1048576;
  unsigned short* wht = uzr + 2*1048576;
  float* h_n   = (float*)(wht + 1048576);
  float* x_n   = h_n + NROW;
  float* rph_n = x_n + NROW;
  // d_out as scratch: C2 = [M][2048] bf16: Mz_x|Mr_x -> rph|Mh -> fp32 out
  unsigned short* C2 = (unsigned short*)d_out;

  cast_norm_k<<<dim3(4096), dim3(256), 0, stream>>>(hidden, hbf, h_n);
  cast_norm_k<<<dim3(4096), dim3(256), 0, stream>>>(hyp_x, xbf, x_n);

  dim3 wg(32, 32), wb(32, 8);
  wcast_k<<<wg, wb, 0, stream>>>(w_z, wzr);
  wcast_k<<<wg, wb, 0, stream>>>(w_r, wzr + 1048576);
  wcast_k<<<wg, wb, 0, stream>>>(u_z, uzr);
  wcast_k<<<wg, wb, 0, stream>>>(u_r, uzr + 1048576);
  wcast_k<<<wg, wb, 0, stream>>>(w_h, wht);

  gemm_k<<<dim3(8,128), dim3(512), 0, stream>>>(hbf, wzr, C1, 1024, 2048); // Mz_h|Mr_h
  gemm_k<<<dim3(8,128), dim3(512), 0, stream>>>(xbf, uzr, C2, 1024, 2048); // Mz_x|Mr_x

  epi1_k<<<dim3(4096), dim3(256), 0, stream>>>(C1, C2, hbf, b_z, b_r, h_n, x_n, rph_n);

  // Mh = rph @ Wh : reads C2 lo half (rph), writes C2 hi half (over dead Mr_x)
  gemm_k<<<dim3(4,128), dim3(512), 0, stream>>>(C2, wht, C2 + 1024, 2048, 2048);

  epi2_k<<<dim3(4096), dim3(256), 0, stream>>>(C1, C2, hbf, b_h, rph_n, out);
}

// Round 6
// 335.336 us; speedup vs baseline: 1.3514x; 1.0360x over previous
//
#include <hip/hip_runtime.h>
#include <stdint.h>

#define EPSF 1e-5f
#define MAXNF (1.0f - 1e-5f)

typedef __attribute__((ext_vector_type(8))) short short8;
typedef __attribute__((ext_vector_type(4))) float floatx4;

__device__ __forceinline__ unsigned short f2bf(float f){
  union { float f; uint32_t u; } v; v.f = f;
  return (unsigned short)((v.u + 0x7FFFu + ((v.u >> 16) & 1u)) >> 16);
}
__device__ __forceinline__ float bf_lo(uint32_t u){
  union { uint32_t u; float f; } v; v.u = u << 16; return v.f;
}
__device__ __forceinline__ float bf_hi(uint32_t u){
  union { uint32_t u; float f; } v; v.u = u & 0xffff0000u; return v.f;
}
// HW packed f32->bf16 (RNE)
__device__ __forceinline__ uint32_t cvtpk(float lo, float hi){
  uint32_t r; asm("v_cvt_pk_bf16_f32 %0, %1, %2" : "=v"(r) : "v"(lo), "v"(hi));
  return r;
}
__device__ __forceinline__ float fsqrt(float x){ return __builtin_amdgcn_sqrtf(x); }

// ball b (4 bf16) load/store at 8B granularity — stride-64-ball interleave keeps
// lane j at byte 8j: perfectly coalesced.
__device__ __forceinline__ float4 ld_ball(const unsigned short* rowp, int b){
  const uint2 u = *(const uint2*)(rowp + 4*b);
  return make_float4(bf_lo(u.x), bf_hi(u.x), bf_lo(u.y), bf_hi(u.y));
}
__device__ __forceinline__ void st_ball(unsigned short* rowp, int b, float4 f){
  uint2 u; u.x = cvtpk(f.x, f.y); u.y = cvtpk(f.z, f.w);
  *(uint2*)(rowp + 4*b) = u;
}

__device__ __forceinline__ void gload16(const void* g, void* l){
  __builtin_amdgcn_global_load_lds(
      (__attribute__((address_space(1))) void*)(uintptr_t)g,
      (__attribute__((address_space(3))) void*)l, 16, 0, 0);
}

// ---- fast transcendentals (v_exp/v_log/v_rcp; ~1e-6 rel err vs 1.7e-3 tol) ----
__device__ __forceinline__ float fatanh(float x){           // x in [EPSF, MAXNF]
  return 0.5f * __logf(__fdividef(1.f + x, 1.f - x));
}
__device__ __forceinline__ float ftanh_pos(float x){        // x >= 0
  const float t = __expf(-2.f * x);
  return __fdividef(1.f - t, 1.f + t);
}
__device__ __forceinline__ float fsig(float x){
  return __fdividef(1.f, 1.f + __expf(-x));
}

// full-wave (64) butterfly sum; result in all lanes
__device__ __forceinline__ float wsum(float v){
  #pragma unroll
  for (int o = 32; o; o >>= 1) v += __shfl_xor(v, o);
  return v;
}

// ---------------- per-ball Mobius helpers ----------------
__device__ __forceinline__ float dot4(const float4 a, const float4 b){
  return a.x*b.x + a.y*b.y + a.z*b.z + a.w*b.w;
}
__device__ __forceinline__ float4 scal4(const float4 a, float s){
  return make_float4(a.x*s, a.y*s, a.z*s, a.w*s);
}
__device__ __forceinline__ float clipn(float n){ return fminf(fmaxf(n, EPSF), MAXNF); }

__device__ __forceinline__ float4 mob_add4(const float4 u, const float4 v){
  const float uv = dot4(u,v), uu = dot4(u,u), vv = dot4(v,v);
  const float cu = 1.f + 2.f*uv + vv, cv = 1.f - uu;
  const float inv = __fdividef(1.f, fmaxf(1.f + 2.f*uv + uu*vv, EPSF));
  return make_float4((cu*u.x + cv*v.x)*inv, (cu*u.y + cv*v.y)*inv,
                     (cu*u.z + cv*v.z)*inv, (cu*u.w + cv*v.w)*inv);
}
__device__ __forceinline__ float4 logmap_sig4(const float4 y){
  const float nc = clipn(fsqrt(dot4(y,y)));
  const float s = __fdividef(fatanh(nc), nc);
  return make_float4(fsig(s*y.x), fsig(s*y.y), fsig(s*y.z), fsig(s*y.w));
}
__device__ __forceinline__ float4 mob_pp4(const float4 x, const float4 u){
  const float4 ux = make_float4(u.x*x.x, u.y*x.y, u.z*x.z, u.w*x.w);
  const float xn = clipn(fsqrt(dot4(x,x)));
  const float uxn = fmaxf(fsqrt(dot4(ux,ux)), EPSF);
  const float s = __fdividef(ftanh_pos(__fdividef(uxn, xn) * fatanh(xn)), uxn);
  return scal4(ux, s);
}

// ---------------- cast to bf16 + per-row norm (wave-per-row) ----------------
__global__ void cast_norm_k(const float* __restrict__ X, unsigned short* __restrict__ Xbf,
                            float* __restrict__ nrm){
  const int lane = threadIdx.x & 63;
  const int row  = blockIdx.x*4 + (threadIdx.x >> 6);
  const float4* xr = (const float4*)(X + (size_t)row*1024);
  unsigned short* br_ = Xbf + (size_t)row*1024;
  float ss = 0.f;
  #pragma unroll
  for (int i = 0; i < 4; ++i){
    const int b = lane + 64*i;
    const float4 v = xr[b];
    st_ball(br_, b, v);
    ss += dot4(v, v);
  }
  ss = wsum(ss);
  if (lane == 0) nrm[row] = fsqrt(ss);
}

// ---------------- weight transpose+cast: Wt[n][k] = bf16(W[k][n]) ----------------
__global__ void wcast_k(const float* __restrict__ W, unsigned short* __restrict__ Wt){
  __shared__ float tile[32][33];
  const int tx = threadIdx.x, ty = threadIdx.y;     // 32 x 8
  const int k0 = blockIdx.x * 32, n0 = blockIdx.y * 32;
  #pragma unroll
  for (int i = 0; i < 4; ++i)
    tile[ty + i*8][tx] = W[(size_t)(k0 + ty + i*8) * 1024 + n0 + tx];
  __syncthreads();
  #pragma unroll
  for (int i = 0; i < 4; ++i)
    Wt[(size_t)(n0 + ty + i*8) * 1024 + k0 + tx] = f2bf(tile[tx][ty + i*8]);
}

// ---------------- bf16 MFMA GEMM: C[m][n] = bf16( sum_k A[m][k] * Bt[n][k] ) ----------------
// BM=128, BN=256, BK=32, K=1024. 1D grid with XCD-chunked swizzle: XCD r owns
// row-panels [16r,16r+16) for all column blocks -> A panel lands in ONE L2.
// LDS chunk swizzle f(r)=(r>>1)&3: bank base of row r is 16*(r&1), so
// (parity, f) covers all 8 bank groups over 16 consecutive rows -> uniform
// 2-way (free, m136). Round-5's f(r)=r&3 was a 4-way conflict (8.4M/dispatch).
#define GBM 128
#define GBN 256
#define GBK 32
#define GKD 1024

__global__ __launch_bounds__(512) void gemm_k(const unsigned short* __restrict__ A,
                                              const unsigned short* __restrict__ Bt,
                                              unsigned short* __restrict__ C,
                                              int lda, int ldc, int lnx){
  __shared__ unsigned short smem[2*4096 + 2*8192];   // A: 2x(128x32), B: 2x(256x32)
  unsigned short* As = smem;
  unsigned short* Bs = smem + 2*4096;
  const int tid = threadIdx.x;
  const int lane = tid & 63, w = tid >> 6;
  const int wr = w >> 2, wc = w & 3;
  const int lr = lane & 15, kg = lane >> 4;
  // XCD-chunked bijective swizzle (8 XCDs, 128 row-panels, 2^lnx col-panels)
  const int wg  = blockIdx.x;
  const int xcd = wg & 7, q = wg >> 3;
  const int bx  = q & ((1 << lnx) - 1);
  const int by  = (xcd << 4) + (q >> lnx);
  const int row0 = by * GBM, col0 = bx * GBN;

  int aoff[4], boff[4];
  #pragma unroll
  for (int a = 0; a < 4; ++a){
    const int r = wr*64 + a*16 + lr;
    aoff[a] = r*32 + ((kg ^ ((r >> 1) & 3)) << 3);
  }
  #pragma unroll
  for (int b = 0; b < 4; ++b){
    const int r = wc*64 + b*16 + lr;
    boff[b] = r*32 + ((kg ^ ((r >> 1) & 3)) << 3);
  }

  floatx4 acc[4][4] = {};

  auto stage = [&](int buf, int kt){
    {
      const int flat = tid;                       // 512 chunks for A tile
      const int r = flat >> 2, cp = flat & 3, c = cp ^ ((r >> 1) & 3);
      gload16(A + (size_t)(row0 + r)*lda + kt*GBK + c*8, As + buf*4096 + flat*8);
    }
    #pragma unroll
    for (int i = 0; i < 2; ++i){                  // 1024 chunks for B tile
      const int flat = i*512 + tid;
      const int r = flat >> 2, cp = flat & 3, c = cp ^ ((r >> 1) & 3);
      gload16(Bt + (size_t)(col0 + r)*GKD + kt*GBK + c*8, Bs + buf*8192 + flat*8);
    }
  };

  stage(0, 0);
  __syncthreads();
  int cur = 0;
  for (int kt = 0; kt < GKD/GBK; ++kt){
    if (kt + 1 < GKD/GBK) stage(cur ^ 1, kt + 1);
    const unsigned short* as = As + cur*4096;
    const unsigned short* bs = Bs + cur*8192;
    short8 af[4], bfv[4];
    #pragma unroll
    for (int a = 0; a < 4; ++a) af[a] = *(const short8*)(as + aoff[a]);
    #pragma unroll
    for (int b = 0; b < 4; ++b) bfv[b] = *(const short8*)(bs + boff[b]);
    #pragma unroll
    for (int a = 0; a < 4; ++a)
      #pragma unroll
      for (int b = 0; b < 4; ++b)
        acc[a][b] = __builtin_amdgcn_mfma_f32_16x16x32_bf16(af[a], bfv[b], acc[a][b], 0, 0, 0);
    __syncthreads();
    cur ^= 1;
  }

  const int crow0 = row0 + wr*64;
  const int ccol = col0 + wc*64 + lr;
  #pragma unroll
  for (int a = 0; a < 4; ++a){
    #pragma unroll
    for (int j = 0; j < 4; ++j){
      const int r = crow0 + a*16 + kg*4 + j;
      unsigned short* cp = C + (size_t)r*ldc + ccol;
      #pragma unroll
      for (int b = 0; b < 4; ++b) cp[b*16] = f2bf(acc[a][b][j]);
    }
  }
}

// ---------------- epilogue 1 (wave-per-row, lane owns balls lane+64i) ----------------
// C1 = [M][2048]: Mz_h|Mr_h -> z|Ux ;  C2 = [M][2048] (d_out): Mz_x|Mr_x -> rph|dead
__global__ __launch_bounds__(256) __attribute__((amdgpu_waves_per_eu(4,4)))
void epi1_k(unsigned short* C1, unsigned short* C2, const unsigned short* hbf,
            const float* bz, const float* br,
            const float* h_nrm, const float* x_nrm, float* rph_nrm){
  const int lane = threadIdx.x & 63;
  const int row  = blockIdx.x*4 + (threadIdx.x >> 6);
  unsigned short* c1lo = C1 + (size_t)row*2048;
  unsigned short* c1hi = c1lo + 1024;
  unsigned short* c2lo = C2 + (size_t)row*2048;
  unsigned short* c2hi = c2lo + 1024;
  const unsigned short* hr = hbf + (size_t)row*1024;

  float4 mzh[4], mrh[4], mzx[4], mrx[4];
  float s0 = 0.f, s1 = 0.f, s2 = 0.f, s3 = 0.f;
  #pragma unroll
  for (int i = 0; i < 4; ++i){
    const int b = lane + 64*i;
    mzh[i] = ld_ball(c1lo, b); mrh[i] = ld_ball(c1hi, b);
    mzx[i] = ld_ball(c2lo, b); mrx[i] = ld_ball(c2hi, b);
    s0 += dot4(mzh[i], mzh[i]); s1 += dot4(mzx[i], mzx[i]);
    s2 += dot4(mrh[i], mrh[i]); s3 += dot4(mrx[i], mrx[i]);
  }
  s0 = wsum(s0); s1 = wsum(s1); s2 = wsum(s2); s3 = wsum(s3);

  const float nMzh = fmaxf(fsqrt(s0), EPSF);
  const float nMzx = fmaxf(fsqrt(s1), EPSF);
  const float nMrh = fmaxf(fsqrt(s2), EPSF);
  const float nMrx = fmaxf(fsqrt(s3), EPSF);
  const float hnc = clipn(h_nrm[row]), xnc = clipn(x_nrm[row]);
  const float atH = fatanh(hnc), atX = fatanh(xnc);
  const float swz = __fdividef(ftanh_pos(__fdividef(nMzh, hnc)*atH), nMzh);
  const float suz = __fdividef(ftanh_pos(__fdividef(nMzx, xnc)*atX), nMzx);
  const float swr = __fdividef(ftanh_pos(__fdividef(nMrh, hnc)*atH), nMrh);
  const float sur = __fdividef(ftanh_pos(__fdividef(nMrx, xnc)*atX), nMrx);

  float sr = 0.f;
  #pragma unroll
  for (int i = 0; i < 4; ++i){
    const int b = lane + 64*i;
    const float4 bz4 = ((const float4*)bz)[b];
    const float4 br4 = ((const float4*)br)[b];
    const float4 z4  = logmap_sig4(mob_add4(mob_add4(scal4(mzh[i],swz), scal4(mzx[i],suz)), bz4));
    const float4 UxR = scal4(mrx[i], sur);
    const float4 r4  = logmap_sig4(mob_add4(mob_add4(scal4(mrh[i],swr), UxR), br4));
    st_ball(c1lo, b, z4);                        // z over Mz_h (same lane, same bytes)
    st_ball(c1hi, b, UxR);                       // Ux over Mr_h
    const float4 h4  = ld_ball(hr, b);
    const float4 rph = mob_pp4(h4, r4);
    st_ball(c2lo, b, rph);                       // rph over Mz_x
    sr += dot4(rph, rph);
  }
  sr = wsum(sr);
  if (lane == 0) rph_nrm[row] = fsqrt(sr);
}

// ---------------- epilogue 2 (wave-per-row): h_tilde, final new_h ----------------
// Mh lives in C2 hi half; out (fp32) overwrites all of C2 — safe: every Mh load
// feeds swh (computed before the first store) so loads complete first, and one
// wave owns the whole row (no cross-wave overlap).
__global__ __launch_bounds__(256) __attribute__((amdgpu_waves_per_eu(4,4)))
void epi2_k(const unsigned short* C1, const unsigned short* C2,
            const unsigned short* hbf, const float* bh,
            const float* rph_nrm, float* out){
  const int lane = threadIdx.x & 63;
  const int row  = blockIdx.x*4 + (threadIdx.x >> 6);
  const unsigned short* c1lo = C1 + (size_t)row*2048;
  const unsigned short* c1hi = c1lo + 1024;
  const unsigned short* c2hi = C2 + (size_t)row*2048 + 1024;
  const unsigned short* hr = hbf + (size_t)row*1024;
  float4* outr = (float4*)(out + (size_t)row*1024);

  float4 mh[4];
  float ss = 0.f;
  #pragma unroll
  for (int i = 0; i < 4; ++i){
    mh[i] = ld_ball(c2hi, lane + 64*i);
    ss += dot4(mh[i], mh[i]);
  }
  ss = wsum(ss);
  const float nMh = fmaxf(fsqrt(ss), EPSF);
  const float rnc = clipn(rph_nrm[row]);
  const float swh = __fdividef(ftanh_pos(__fdividef(nMh, rnc)*fatanh(rnc)), nMh);

  #pragma unroll
  for (int i = 0; i < 4; ++i){
    const int b = lane + 64*i;
    const float4 WhH = scal4(mh[i], swh);
    const float4 Ux4 = ld_ball(c1hi, b);
    const float4 bh4 = ((const float4*)bh)[b];
    const float4 ht  = mob_add4(mob_add4(WhH, Ux4), bh4);
    const float4 h4  = ld_ball(hr, b);
    const float4 nh4 = make_float4(-h4.x, -h4.y, -h4.z, -h4.w);
    const float4 m4  = mob_add4(nh4, ht);
    const float4 z4  = ld_ball(c1lo, b);
    const float4 p4  = mob_pp4(m4, z4);
    outr[b] = mob_add4(h4, p4);
  }
}

extern "C" void kernel_launch(void* const* d_in, const int* in_sizes, int n_in,
                              void* d_out, int out_size, void* d_ws, size_t ws_size,
                              hipStream_t stream) {
  (void)in_sizes; (void)n_in; (void)out_size; (void)ws_size;
  const float* hyp_x  = (const float*)d_in[0];
  const float* hidden = (const float*)d_in[1];
  const float* w_z = (const float*)d_in[2];
  const float* w_r = (const float*)d_in[3];
  const float* w_h = (const float*)d_in[4];
  const float* u_z = (const float*)d_in[5];
  const float* u_r = (const float*)d_in[6];
  // d_in[7] = u_h unused by the reference (it uses u_r for h_tilde)
  const float* b_z = (const float*)d_in[8];
  const float* b_r = (const float*)d_in[9];
  const float* b_h = (const float*)d_in[10];
  float* out = (float*)d_out;

  const size_t NROW = 16384, MAT = NROW*1024;
  // ws layout (144.5 MiB): hbf 32 + xbf 32 + C1 64 + weights 10 + norms
  unsigned short* hbf = (unsigned short*)d_ws;   // bf16(hidden) — stays live to the end
  unsigned short* xbf = hbf + MAT;
  unsigned short* C1  = xbf + MAT;               // [M][2048]: Mz_h|Mr_h -> z|Ux
  unsigned short* wzr = C1 + 2*MAT;              // [2048][1024]: wzt | wrt
  unsigned short* uzr = wzr + 2*1048576;
  unsigned short* wht = uzr + 2*1048576;
  float* h_n   = (float*)(wht + 1048576);
  float* x_n   = h_n + NROW;
  float* rph_n = x_n + NROW;
  // d_out as scratch: C2 = [M][2048] bf16: Mz_x|Mr_x -> rph|Mh -> fp32 out
  unsigned short* C2 = (unsigned short*)d_out;

  cast_norm_k<<<dim3(4096), dim3(256), 0, stream>>>(hidden, hbf, h_n);
  cast_norm_k<<<dim3(4096), dim3(256), 0, stream>>>(hyp_x, xbf, x_n);

  dim3 wg(32, 32), wb(32, 8);
  wcast_k<<<wg, wb, 0, stream>>>(w_z, wzr);
  wcast_k<<<wg, wb, 0, stream>>>(w_r, wzr + 1048576);
  wcast_k<<<wg, wb, 0, stream>>>(u_z, uzr);
  wcast_k<<<wg, wb, 0, stream>>>(u_r, uzr + 1048576);
  wcast_k<<<wg, wb, 0, stream>>>(w_h, wht);

  // 1D grids: 8 col-panels * 128 row-panels (lnx=3); Wh GEMM: 4 * 128 (lnx=2)
  gemm_k<<<dim3(1024), dim3(512), 0, stream>>>(hbf, wzr, C1, 1024, 2048, 3); // Mz_h|Mr_h
  gemm_k<<<dim3(1024), dim3(512), 0, stream>>>(xbf, uzr, C2, 1024, 2048, 3); // Mz_x|Mr_x

  epi1_k<<<dim3(4096), dim3(256), 0, stream>>>(C1, C2, hbf, b_z, b_r, h_n, x_n, rph_n);

  // Mh = rph @ Wh : reads C2 lo half (rph), writes C2 hi half (over dead Mr_x)
  gemm_k<<<dim3(512), dim3(512), 0, stream>>>(C2, wht, C2 + 1024, 2048, 2048, 2);

  epi2_k<<<dim3(4096), dim3(256), 0, stream>>>(C1, C2, hbf, b_h, rph_n, out);
}

// Round 7
// 321.759 us; speedup vs baseline: 1.4084x; 1.0422x over previous
//
#include <hip/hip_runtime.h>
#include <stdint.h>

#define EPSF 1e-5f
#define MAXNF (1.0f - 1e-5f)

typedef __attribute__((ext_vector_type(8))) short short8;
typedef __attribute__((ext_vector_type(4))) float floatx4;

__device__ __forceinline__ unsigned short f2bf(float f){
  union { float f; uint32_t u; } v; v.f = f;
  return (unsigned short)((v.u + 0x7FFFu + ((v.u >> 16) & 1u)) >> 16);
}
__device__ __forceinline__ float bf_lo(uint32_t u){
  union { uint32_t u; float f; } v; v.u = u << 16; return v.f;
}
__device__ __forceinline__ float bf_hi(uint32_t u){
  union { uint32_t u; float f; } v; v.u = u & 0xffff0000u; return v.f;
}
__device__ __forceinline__ uint32_t cvtpk(float lo, float hi){
  uint32_t r; asm("v_cvt_pk_bf16_f32 %0, %1, %2" : "=v"(r) : "v"(lo), "v"(hi));
  return r;
}
__device__ __forceinline__ float fsqrt(float x){ return __builtin_amdgcn_sqrtf(x); }

__device__ __forceinline__ float4 ld_ball(const unsigned short* rowp, int b){
  const uint2 u = *(const uint2*)(rowp + 4*b);
  return make_float4(bf_lo(u.x), bf_hi(u.x), bf_lo(u.y), bf_hi(u.y));
}
__device__ __forceinline__ void st_ball(unsigned short* rowp, int b, float4 f){
  uint2 u; u.x = cvtpk(f.x, f.y); u.y = cvtpk(f.z, f.w);
  *(uint2*)(rowp + 4*b) = u;
}

__device__ __forceinline__ void gload16(const void* g, void* l){
  __builtin_amdgcn_global_load_lds(
      (__attribute__((address_space(1))) void*)(uintptr_t)g,
      (__attribute__((address_space(3))) void*)l, 16, 0, 0);
}

// ---- fast transcendentals (v_exp/v_log/v_rcp; ~1e-6 rel err vs 1.7e-3 tol) ----
__device__ __forceinline__ float fatanh(float x){
  return 0.5f * __logf(__fdividef(1.f + x, 1.f - x));
}
__device__ __forceinline__ float ftanh_pos(float x){
  const float t = __expf(-2.f * x);
  return __fdividef(1.f - t, 1.f + t);
}
__device__ __forceinline__ float fsig(float x){
  return __fdividef(1.f, 1.f + __expf(-x));
}

__device__ __forceinline__ float wsum(float v){
  #pragma unroll
  for (int o = 32; o; o >>= 1) v += __shfl_xor(v, o);
  return v;
}

// ---------------- per-ball Mobius helpers ----------------
__device__ __forceinline__ float dot4(const float4 a, const float4 b){
  return a.x*b.x + a.y*b.y + a.z*b.z + a.w*b.w;
}
__device__ __forceinline__ float4 scal4(const float4 a, float s){
  return make_float4(a.x*s, a.y*s, a.z*s, a.w*s);
}
__device__ __forceinline__ float clipn(float n){ return fminf(fmaxf(n, EPSF), MAXNF); }

__device__ __forceinline__ float4 mob_add4(const float4 u, const float4 v){
  const float uv = dot4(u,v), uu = dot4(u,u), vv = dot4(v,v);
  const float cu = 1.f + 2.f*uv + vv, cv = 1.f - uu;
  const float inv = __fdividef(1.f, fmaxf(1.f + 2.f*uv + uu*vv, EPSF));
  return make_float4((cu*u.x + cv*v.x)*inv, (cu*u.y + cv*v.y)*inv,
                     (cu*u.z + cv*v.z)*inv, (cu*u.w + cv*v.w)*inv);
}
__device__ __forceinline__ float4 logmap_sig4(const float4 y){
  const float nc = clipn(fsqrt(dot4(y,y)));
  const float s = __fdividef(fatanh(nc), nc);
  return make_float4(fsig(s*y.x), fsig(s*y.y), fsig(s*y.z), fsig(s*y.w));
}
__device__ __forceinline__ float4 mob_pp4(const float4 x, const float4 u){
  const float4 ux = make_float4(u.x*x.x, u.y*x.y, u.z*x.z, u.w*x.w);
  const float xn = clipn(fsqrt(dot4(x,x)));
  const float uxn = fmaxf(fsqrt(dot4(ux,ux)), EPSF);
  const float s = __fdividef(ftanh_pos(__fdividef(uxn, xn) * fatanh(xn)), uxn);
  return scal4(ux, s);
}

// ---------------- cast to bf16 + per-row norm (wave-per-row) ----------------
__global__ void cast_norm_k(const float* __restrict__ X, unsigned short* __restrict__ Xbf,
                            float* __restrict__ nrm){
  const int lane = threadIdx.x & 63;
  const int row  = blockIdx.x*4 + (threadIdx.x >> 6);
  const float4* xr = (const float4*)(X + (size_t)row*1024);
  unsigned short* br_ = Xbf + (size_t)row*1024;
  float ss = 0.f;
  #pragma unroll
  for (int i = 0; i < 4; ++i){
    const int b = lane + 64*i;
    const float4 v = xr[b];
    st_ball(br_, b, v);
    ss += dot4(v, v);
  }
  ss = wsum(ss);
  if (lane == 0) nrm[row] = fsqrt(ss);
}

// ---------------- weight transpose+cast: Wt[n][k] = bf16(W[k][n]) ----------------
__global__ void wcast_k(const float* __restrict__ W, unsigned short* __restrict__ Wt){
  __shared__ float tile[32][33];
  const int tx = threadIdx.x, ty = threadIdx.y;     // 32 x 8
  const int k0 = blockIdx.x * 32, n0 = blockIdx.y * 32;
  #pragma unroll
  for (int i = 0; i < 4; ++i)
    tile[ty + i*8][tx] = W[(size_t)(k0 + ty + i*8) * 1024 + n0 + tx];
  __syncthreads();
  #pragma unroll
  for (int i = 0; i < 4; ++i)
    Wt[(size_t)(n0 + ty + i*8) * 1024 + k0 + tx] = f2bf(tile[tx][ty + i*8]);
}

// ================= 8-phase 256x256 bf16 MFMA GEMM (T2+T3+T4+T5) =================
// C[m][n] = bf16( sum_k A[m][k] * Bt[n][k] ), K=1024 (16 K-tiles of BK=64).
// 512 thr = 8 waves (2M x 4N), wave tile 128x64 = 8x4 frags of 16x16x32.
// LDS 128 KiB: A 2buf x 256x64, B 2buf x 256x64 (bf16, row=128B).
// Chunk swizzle cc ^= (row&7): pre-swizzled global source (gload_lds dest is
// linear) + swizzled ds_read -> 2-way max (free). Raw s_barrier only — never
// __syncthreads (it would emit the vmcnt(0) drain this schedule exists to kill).
// Counted vmcnt(6) once per K-tile: 3 newest half-tiles stay in flight.
// Stage stagger: A halves read ph1/ph3 -> restaged ph4; B read ph1/ph2 ->
// restaged ph3 (lo) / next-ph1 (hi). Overwrites always >=1 barrier after last read.
#define NT 16

#define BARFENCE do { __builtin_amdgcn_s_barrier(); asm volatile("" ::: "memory"); } while(0)
#define LDA4(dst, MO) do { _Pragma("unroll") for (int m_=0;m_<4;++m_) \
  _Pragma("unroll") for (int k_=0;k_<2;++k_) \
    dst[m_][k_] = *(const short8*)(smem + bufb*32768 + abase + (MO+m_)*2048 + ((((k_<<2)+kg)^x7)<<4)); } while(0)
#define LDB2(dst, NO) do { _Pragma("unroll") for (int n_=0;n_<2;++n_) \
  _Pragma("unroll") for (int k_=0;k_<2;++k_) \
    dst[n_][k_] = *(const short8*)(smem + bufb*32768 + bbase + (NO+n_)*2048 + ((((k_<<2)+kg)^x7)<<4)); } while(0)
#define QUAD(AF, MO, BF, NO) do { _Pragma("unroll") for (int m_=0;m_<4;++m_) \
  _Pragma("unroll") for (int n_=0;n_<2;++n_) \
  _Pragma("unroll") for (int k_=0;k_<2;++k_) \
    acc[MO+m_][NO+n_] = __builtin_amdgcn_mfma_f32_16x16x32_bf16(AF[m_][k_], BF[n_][k_], acc[MO+m_][NO+n_], 0,0,0); } while(0)

__global__ __launch_bounds__(512, 2) void gemm8_k(const unsigned short* __restrict__ A,
                                                  const unsigned short* __restrict__ Bt,
                                                  unsigned short* __restrict__ C,
                                                  int lda, int ldc, int lnx){
  __shared__ unsigned char smem[131072];
  const int tid = threadIdx.x;
  const int lane = tid & 63, w = tid >> 6;
  const int wm = w >> 2, wn = w & 3;
  const int lr = lane & 15, kg = lane >> 4;
  const int x7 = lr & 7;

  // XCD-chunked bijective swizzle: 64 row-panels = 8 per XCD, 2^lnx col-panels
  const int wg  = blockIdx.x;
  const int xcd = wg & 7, q = wg >> 3;
  const int bx  = q & ((1 << lnx) - 1);
  const int by  = (xcd << 3) + (q >> lnx);
  const int row0 = by * 256, col0 = bx * 256;

  const int abase = (wm*128 + lr)*128;          // + buf*32768 + m*2048 + slot*16
  const int bbase = 65536 + (wn*64 + lr)*128;   // + buf*32768 + n*2048 + slot*16

  floatx4 acc[8][4] = {};

  auto stageH = [&](int regionByte, const unsigned short* src, int srow0, int ld, int kt){
    #pragma unroll
    for (int call = 0; call < 2; ++call){
      const int L  = (call << 9) + tid;
      const int rl = L >> 3;
      const int cc = (L & 7) ^ (rl & 7);            // inverse-swizzled source
      gload16(src + (size_t)(srow0 + rl)*ld + kt*64 + cc*8,
              smem + regionByte + L*16);            // linear LDS dest
    }
  };
  auto stageA = [&](int kt, int h){ stageH((kt&1)*32768 + h*16384, A, row0 + h*128, lda, kt); };
  auto stageB = [&](int kt, int h){ stageH(65536 + (kt&1)*32768 + h*16384, Bt, col0 + h*128, 1024, kt); };

  // prologue: tile0 complete (4 half-tiles), tile1 {B-lo, A-lo, A-hi}
  stageA(0,0); stageA(0,1); stageB(0,0); stageB(0,1);
  stageB(1,0); stageA(1,0); stageA(1,1);
  asm volatile("s_waitcnt vmcnt(6)" ::: "memory");   // tile0's 8 loads landed
  __builtin_amdgcn_s_barrier();
  asm volatile("" ::: "memory");

  short8 aL[4][2], aH[4][2], bA[2][2], bB[2][2];

  for (int t = 0; t < NT; ++t){
    const int bufb = t & 1;
    // ---- phase 1: read A[0..3] + B[0..1]; stage (t+1).B-hi -> buf^1
    LDA4(aL, 0); LDB2(bA, 0);
    if (t+1 < NT) stageB(t+1, 1);
    BARFENCE;
    __builtin_amdgcn_s_setprio(1); QUAD(aL, 0, bA, 0); __builtin_amdgcn_s_setprio(0);
    BARFENCE;
    // ---- phase 2: read B[2..3]
    LDB2(bB, 2);
    BARFENCE;
    __builtin_amdgcn_s_setprio(1); QUAD(aL, 0, bB, 2); __builtin_amdgcn_s_setprio(0);
    BARFENCE;
    // ---- phase 3: read A[4..7]; stage (t+2).B-lo -> buf (B reads done ph2)
    LDA4(aH, 4);
    if (t+2 < NT) stageB(t+2, 0);
    BARFENCE;
    __builtin_amdgcn_s_setprio(1); QUAD(aH, 4, bB, 2); __builtin_amdgcn_s_setprio(0);
    BARFENCE;
    // ---- phase 4: stage (t+2).A -> buf (A reads done ph3); counted vmcnt
    if (t+2 < NT){ stageA(t+2, 0); stageA(t+2, 1); }
    if (t+2 < NT)      asm volatile("s_waitcnt vmcnt(6)" ::: "memory"); // t+1 fully landed
    else if (t+1 < NT) asm volatile("s_waitcnt vmcnt(0)" ::: "memory"); // tail drain
    BARFENCE;
    __builtin_amdgcn_s_setprio(1); QUAD(aH, 4, bA, 0); __builtin_amdgcn_s_setprio(0);
    BARFENCE;
  }

  const int crow = row0 + wm*128;
  const int ccol = col0 + wn*64 + lr;
  #pragma unroll
  for (int m = 0; m < 8; ++m){
    #pragma unroll
    for (int j = 0; j < 4; ++j){
      unsigned short* cp = C + (size_t)(crow + m*16 + kg*4 + j)*ldc + ccol;
      #pragma unroll
      for (int n = 0; n < 4; ++n) cp[n*16] = f2bf(acc[m][n][j]);
    }
  }
}

// ---------------- epilogue 1 (wave-per-row, lane owns balls lane+64i) ----------------
// C1 = [M][2048]: Mz_h|Mr_h -> z|Ux ;  C2 = [M][2048] (d_out): Mz_x|Mr_x -> rph|dead
__global__ __launch_bounds__(256) __attribute__((amdgpu_waves_per_eu(4,4)))
void epi1_k(unsigned short* C1, unsigned short* C2, const unsigned short* hbf,
            const float* bz, const float* br,
            const float* h_nrm, const float* x_nrm, float* rph_nrm){
  const int lane = threadIdx.x & 63;
  const int row  = blockIdx.x*4 + (threadIdx.x >> 6);
  unsigned short* c1lo = C1 + (size_t)row*2048;
  unsigned short* c1hi = c1lo + 1024;
  unsigned short* c2lo = C2 + (size_t)row*2048;
  unsigned short* c2hi = c2lo + 1024;
  const unsigned short* hr = hbf + (size_t)row*1024;

  float4 mzh[4], mrh[4], mzx[4], mrx[4];
  float s0 = 0.f, s1 = 0.f, s2 = 0.f, s3 = 0.f;
  #pragma unroll
  for (int i = 0; i < 4; ++i){
    const int b = lane + 64*i;
    mzh[i] = ld_ball(c1lo, b); mrh[i] = ld_ball(c1hi, b);
    mzx[i] = ld_ball(c2lo, b); mrx[i] = ld_ball(c2hi, b);
    s0 += dot4(mzh[i], mzh[i]); s1 += dot4(mzx[i], mzx[i]);
    s2 += dot4(mrh[i], mrh[i]); s3 += dot4(mrx[i], mrx[i]);
  }
  s0 = wsum(s0); s1 = wsum(s1); s2 = wsum(s2); s3 = wsum(s3);

  const float nMzh = fmaxf(fsqrt(s0), EPSF);
  const float nMzx = fmaxf(fsqrt(s1), EPSF);
  const float nMrh = fmaxf(fsqrt(s2), EPSF);
  const float nMrx = fmaxf(fsqrt(s3), EPSF);
  const float hnc = clipn(h_nrm[row]), xnc = clipn(x_nrm[row]);
  const float atH = fatanh(hnc), atX = fatanh(xnc);
  const float swz = __fdividef(ftanh_pos(__fdividef(nMzh, hnc)*atH), nMzh);
  const float suz = __fdividef(ftanh_pos(__fdividef(nMzx, xnc)*atX), nMzx);
  const float swr = __fdividef(ftanh_pos(__fdividef(nMrh, hnc)*atH), nMrh);
  const float sur = __fdividef(ftanh_pos(__fdividef(nMrx, xnc)*atX), nMrx);

  float sr = 0.f;
  #pragma unroll
  for (int i = 0; i < 4; ++i){
    const int b = lane + 64*i;
    const float4 bz4 = ((const float4*)bz)[b];
    const float4 br4 = ((const float4*)br)[b];
    const float4 z4  = logmap_sig4(mob_add4(mob_add4(scal4(mzh[i],swz), scal4(mzx[i],suz)), bz4));
    const float4 UxR = scal4(mrx[i], sur);
    const float4 r4  = logmap_sig4(mob_add4(mob_add4(scal4(mrh[i],swr), UxR), br4));
    st_ball(c1lo, b, z4);
    st_ball(c1hi, b, UxR);
    const float4 h4  = ld_ball(hr, b);
    const float4 rph = mob_pp4(h4, r4);
    st_ball(c2lo, b, rph);
    sr += dot4(rph, rph);
  }
  sr = wsum(sr);
  if (lane == 0) rph_nrm[row] = fsqrt(sr);
}

// ---------------- epilogue 2 (wave-per-row): h_tilde, final new_h ----------------
__global__ __launch_bounds__(256) __attribute__((amdgpu_waves_per_eu(4,4)))
void epi2_k(const unsigned short* C1, const unsigned short* C2,
            const unsigned short* hbf, const float* bh,
            const float* rph_nrm, float* out){
  const int lane = threadIdx.x & 63;
  const int row  = blockIdx.x*4 + (threadIdx.x >> 6);
  const unsigned short* c1lo = C1 + (size_t)row*2048;
  const unsigned short* c1hi = c1lo + 1024;
  const unsigned short* c2hi = C2 + (size_t)row*2048 + 1024;
  const unsigned short* hr = hbf + (size_t)row*1024;
  float4* outr = (float4*)(out + (size_t)row*1024);

  float4 mh[4];
  float ss = 0.f;
  #pragma unroll
  for (int i = 0; i < 4; ++i){
    mh[i] = ld_ball(c2hi, lane + 64*i);
    ss += dot4(mh[i], mh[i]);
  }
  ss = wsum(ss);
  const float nMh = fmaxf(fsqrt(ss), EPSF);
  const float rnc = clipn(rph_nrm[row]);
  const float swh = __fdividef(ftanh_pos(__fdividef(nMh, rnc)*fatanh(rnc)), nMh);

  #pragma unroll
  for (int i = 0; i < 4; ++i){
    const int b = lane + 64*i;
    const float4 WhH = scal4(mh[i], swh);
    const float4 Ux4 = ld_ball(c1hi, b);
    const float4 bh4 = ((const float4*)bh)[b];
    const float4 ht  = mob_add4(mob_add4(WhH, Ux4), bh4);
    const float4 h4  = ld_ball(hr, b);
    const float4 nh4 = make_float4(-h4.x, -h4.y, -h4.z, -h4.w);
    const float4 m4  = mob_add4(nh4, ht);
    const float4 z4  = ld_ball(c1lo, b);
    const float4 p4  = mob_pp4(m4, z4);
    outr[b] = mob_add4(h4, p4);
  }
}

extern "C" void kernel_launch(void* const* d_in, const int* in_sizes, int n_in,
                              void* d_out, int out_size, void* d_ws, size_t ws_size,
                              hipStream_t stream) {
  (void)in_sizes; (void)n_in; (void)out_size; (void)ws_size;
  const float* hyp_x  = (const float*)d_in[0];
  const float* hidden = (const float*)d_in[1];
  const float* w_z = (const float*)d_in[2];
  const float* w_r = (const float*)d_in[3];
  const float* w_h = (const float*)d_in[4];
  const float* u_z = (const float*)d_in[5];
  const float* u_r = (const float*)d_in[6];
  // d_in[7] = u_h unused by the reference (it uses u_r for h_tilde)
  const float* b_z = (const float*)d_in[8];
  const float* b_r = (const float*)d_in[9];
  const float* b_h = (const float*)d_in[10];
  float* out = (float*)d_out;

  const size_t NROW = 16384, MAT = NROW*1024;
  unsigned short* hbf = (unsigned short*)d_ws;   // bf16(hidden) — live to the end
  unsigned short* xbf = hbf + MAT;
  unsigned short* C1  = xbf + MAT;               // [M][2048]: Mz_h|Mr_h -> z|Ux
  unsigned short* wzr = C1 + 2*MAT;              // [2048][1024]: wzt | wrt
  unsigned short* uzr = wzr + 2*1048576;
  unsigned short* wht = uzr + 2*1048576;
  float* h_n   = (float*)(wht + 1048576);
  float* x_n   = h_n + NROW;
  float* rph_n = x_n + NROW;
  unsigned short* C2 = (unsigned short*)d_out;   // [M][2048]: Mz_x|Mr_x -> rph|Mh -> fp32 out

  cast_norm_k<<<dim3(4096), dim3(256), 0, stream>>>(hidden, hbf, h_n);
  cast_norm_k<<<dim3(4096), dim3(256), 0, stream>>>(hyp_x, xbf, x_n);

  dim3 wg(32, 32), wb(32, 8);
  wcast_k<<<wg, wb, 0, stream>>>(w_z, wzr);
  wcast_k<<<wg, wb, 0, stream>>>(w_r, wzr + 1048576);
  wcast_k<<<wg, wb, 0, stream>>>(u_z, uzr);
  wcast_k<<<wg, wb, 0, stream>>>(u_r, uzr + 1048576);
  wcast_k<<<wg, wb, 0, stream>>>(w_h, wht);

  // 64 row-panels x 8 col-panels = 512 blocks (lnx=3); Wh: x4 cols = 256 (lnx=2)
  gemm8_k<<<dim3(512), dim3(512), 0, stream>>>(hbf, wzr, C1, 1024, 2048, 3); // Mz_h|Mr_h
  gemm8_k<<<dim3(512), dim3(512), 0, stream>>>(xbf, uzr, C2, 1024, 2048, 3); // Mz_x|Mr_x

  epi1_k<<<dim3(4096), dim3(256), 0, stream>>>(C1, C2, hbf, b_z, b_r, h_n, x_n, rph_n);

  // Mh = rph @ Wh : reads C2 lo half (rph), writes C2 hi half (over dead Mr_x)
  gemm8_k<<<dim3(256), dim3(512), 0, stream>>>(C2, wht, C2 + 1024, 2048, 2048, 2);

  epi2_k<<<dim3(4096), dim3(256), 0, stream>>>(C1, C2, hbf, b_h, rph_n, out);
}